// Round 8
// baseline (1324.804 us; speedup 1.0000x reference)
//
#include <hip/hip_runtime.h>

#define DEV __device__ __forceinline__

typedef unsigned short u16;
typedef __bf16 bf16x8 __attribute__((ext_vector_type(8)));
typedef bf16x8 __attribute__((may_alias)) bf16x8a;
typedef float f32x4 __attribute__((ext_vector_type(4)));
typedef float f32x16 __attribute__((ext_vector_type(16)));

constexpr int NB = 4, NS = 2048, NE = 1024, NH = 4, NDH = 256, NF = 4096;
constexpr int NR = NB * NS;  // 8192 rows

DEV u16 f2bf(float f) {
  unsigned u = __float_as_uint(f);
  u += 0x7fff + ((u >> 16) & 1);
  return (u16)(u >> 16);
}

DEV f32x4 mfma16(bf16x8 a, bf16x8 b, f32x4 c) {
  return __builtin_amdgcn_mfma_f32_16x16x32_bf16(a, b, c, 0, 0, 0);
}
DEV f32x16 mfma32(bf16x8 a, bf16x8 b, f32x16 c) {
  return __builtin_amdgcn_mfma_f32_32x32x16_bf16(a, b, c, 0, 0, 0);
}

DEV bf16x8 ldfrag(const u16* p) { return *(const bf16x8a*)p; }

DEV void gload_lds16(const void* g, void* l) {
  __builtin_amdgcn_global_load_lds(
      (const __attribute__((address_space(1))) void*)g,
      (__attribute__((address_space(3))) void*)l, 16, 0, 0);
}

DEV void blockbar() {
  asm volatile("" ::: "memory");
  __builtin_amdgcn_s_barrier();
  asm volatile("" ::: "memory");
}

DEV unsigned packbf(float a, float b) {
  union { __bf16 h[2]; unsigned u; } x;
  x.h[0] = (__bf16)a; x.h[1] = (__bf16)b;
  return x.u;
}

// ---------------- elementwise cast f32 -> bf16 ----------------
__global__ void cast_f32_bf16(const float* __restrict__ in, u16* __restrict__ out, int n4) {
  int i = blockIdx.x * 256 + threadIdx.x;
  if (i >= n4) return;
  float4 v = ((const float4*)in)[i];
  ushort4 o;
  o.x = f2bf(v.x); o.y = f2bf(v.y); o.z = f2bf(v.z); o.w = f2bf(v.w);
  ((ushort4*)out)[i] = o;
}

// ---------------- batched transpose + cast: in[z][R][C] f32 -> out[z][C][R] bf16 ----------------
__global__ void transpose_cast(const float* __restrict__ in, u16* __restrict__ out, int R, int C) {
  __shared__ float t[32][33];
  size_t base = (size_t)blockIdx.z * R * C;
  int c0 = blockIdx.x * 32, r0 = blockIdx.y * 32;
  int x = threadIdx.x;
  for (int yy = threadIdx.y; yy < 32; yy += 8)
    t[yy][x] = in[base + (size_t)(r0 + yy) * C + c0 + x];
  __syncthreads();
  for (int yy = threadIdx.y; yy < 32; yy += 8)
    out[base + (size_t)(c0 + yy) * R + r0 + x] = f2bf(t[x][yy]);
}

// ---------------- K repack: K[row=key][h*256+d] -> KF[bh][d8][key][8] ----------------
__global__ void repack_k(const u16* __restrict__ K, int kstride, u16* __restrict__ KF) {
  __shared__ u16 t[32][40];
  int bh = blockIdx.z, b = bh >> 2, h = bh & 3;
  int k0 = blockIdx.x * 32, d0 = blockIdx.y * 32;
  int x = threadIdx.x, y = threadIdx.y;
  for (int key = y; key < 32; key += 8)
    t[key][x] = K[(size_t)(b * NS + k0 + key) * kstride + h * NDH + d0 + x];
  __syncthreads();
  if (y < 4) {
    int d8 = (d0 >> 3) + y;
    uint4 v = *(const uint4*)&t[x][y * 8];
    *(uint4*)&KF[(((size_t)bh * 32 + d8) * NS + k0 + x) * 8] = v;
  }
}

// ---------------- V repack: V[row=key][h*256+d] -> VF[bh][key8][d][8] ----------------
__global__ void repack_v(const u16* __restrict__ V, int vstride, u16* __restrict__ VF) {
  __shared__ u16 t[32][40];
  int bh = blockIdx.z, b = bh >> 2, h = bh & 3;
  int k0 = blockIdx.x * 32, d0 = blockIdx.y * 32;
  int x = threadIdx.x, y = threadIdx.y;
  for (int key = y; key < 32; key += 8)
    t[key][x] = V[(size_t)(b * NS + k0 + key) * vstride + h * NDH + d0 + x];
  __syncthreads();
  if (y < 4) {
    int key8 = (k0 >> 3) + y;
    union { u16 h[8]; uint4 v; } val;
#pragma unroll
    for (int kk = 0; kk < 8; kk++) val.h[kk] = t[y * 8 + kk][x];
    *(uint4*)&VF[(((size_t)bh * 256 + key8) * 256 + d0 + x) * 8] = val.v;
  }
}

// ---------------- small f32 copy (bias packing) ----------------
__global__ void copy_f32(const float* __restrict__ s, float* __restrict__ d, int n) {
  int i = blockIdx.x * 256 + threadIdx.x;
  if (i < n) d[i] = s[i];
}

// ---------------- 4-region pipelined GEMM: C[M,N] = A[M,K] * Bt[N,K]^T ----------------
template<int BN, int OUTF32, int RELU>
__global__ __launch_bounds__(512, 1)
void gemm4r(const u16* __restrict__ A, const u16* __restrict__ Bt,
            const float* __restrict__ bias, const float* __restrict__ res,
            float* __restrict__ outF, u16* __restrict__ outB,
            int M, int N, int K)
{
  constexpr int NFRAG = BN / 64;
  constexpr int BREG = BN * 32;
  __shared__ __align__(16) u16 smem[32768 + 4 * BREG];

  int tid = threadIdx.x, w = tid >> 6, lane = tid & 63;
  int lr = lane & 15, lk = lane >> 4;
  int wm = w >> 2, wn = w & 3;

  int flat = blockIdx.y * gridDim.x + blockIdx.x;
  int cpx = (gridDim.x * gridDim.y) >> 3;
  int swz = (flat & 7) * cpx + (flat >> 3);
  int bx = swz % gridDim.x, by = swz / gridDim.x;
  int rowBlk = by * 256, colBlk = bx * BN;

  f32x4 acc[8][NFRAG];
#pragma unroll
  for (int f = 0; f < 8; f++)
#pragma unroll
    for (int n = 0; n < NFRAG; n++) acc[f][n] = (f32x4){0.f, 0.f, 0.f, 0.f};

  const u16* gA = A + (size_t)rowBlk * K;
  const u16* gB = Bt + (size_t)colBlk * K;

  int Rl = lane >> 3, sl = lane & 7;

  auto stage = [&](int hs) {
    int reg = hs & 3;
    int k0 = hs * 32;
#pragma unroll
    for (int j = 0; j < 2; j++) {
      int Rbase = j * 64 + w * 8;
      int R = Rbase + Rl;
      int p = sl ^ (R & 7);
      int r = 2 * R + (p >> 2), g = p & 3;
      gload_lds16(gA + (size_t)r * K + k0 + g * 8,
                  &smem[reg * 8192 + Rbase * 64]);
    }
#pragma unroll
    for (int j = 0; j < (BN == 256 ? 2 : 1); j++) {
      int Rbase = j * 64 + w * 8;
      int R = Rbase + Rl;
      int p = sl ^ (R & 7);
      int r = 2 * R + (p >> 2), g = p & 3;
      gload_lds16(gB + (size_t)r * K + k0 + g * 8,
                  &smem[32768 + reg * BREG + Rbase * 64]);
    }
  };

  int NH32 = K >> 5;
  stage(0); stage(1); stage(2);

  for (int hs = 0; hs < NH32; hs++) {
    if (hs + 3 < NH32) stage(hs + 3);
    int rem = NH32 - 1 - hs;
    if (rem > 3) rem = 3;
    if (BN == 256) {
      if (rem == 3)      asm volatile("s_waitcnt vmcnt(12)" ::: "memory");
      else if (rem == 2) asm volatile("s_waitcnt vmcnt(8)" ::: "memory");
      else if (rem == 1) asm volatile("s_waitcnt vmcnt(4)" ::: "memory");
      else               asm volatile("s_waitcnt vmcnt(0)" ::: "memory");
    } else {
      if (rem == 3)      asm volatile("s_waitcnt vmcnt(9)" ::: "memory");
      else if (rem == 2) asm volatile("s_waitcnt vmcnt(6)" ::: "memory");
      else if (rem == 1) asm volatile("s_waitcnt vmcnt(3)" ::: "memory");
      else               asm volatile("s_waitcnt vmcnt(0)" ::: "memory");
    }
    blockbar();

    int reg = hs & 3;
    const u16* Ar = &smem[reg * 8192];
    const u16* Br = &smem[32768 + reg * BREG];
    bf16x8 af[8], bfr[NFRAG];
#pragma unroll
    for (int f = 0; f < 8; f++) {
      int rowA = wm * 128 + f * 16 + lr;
      af[f] = ldfrag(&Ar[(rowA >> 1) * 64 +
                         (((((rowA & 1) << 2) | lk) ^ ((rowA >> 1) & 7)) * 8)]);
    }
#pragma unroll
    for (int n = 0; n < NFRAG; n++) {
      int rowB = wn * (BN >> 2) + n * 16 + lr;
      bfr[n] = ldfrag(&Br[(rowB >> 1) * 64 +
                          (((((rowB & 1) << 2) | lk) ^ ((rowB >> 1) & 7)) * 8)]);
    }
    asm volatile("s_waitcnt lgkmcnt(0)" ::: "memory");
    blockbar();

    __builtin_amdgcn_s_setprio(1);
#pragma unroll
    for (int f = 0; f < 8; f++)
#pragma unroll
      for (int n = 0; n < NFRAG; n++)
        acc[f][n] = mfma16(af[f], bfr[n], acc[f][n]);
    __builtin_amdgcn_s_setprio(0);
  }

  int orow0 = rowBlk + wm * 128;
  int ocol0 = colBlk + wn * (BN >> 2);
#pragma unroll
  for (int n = 0; n < NFRAG; n++) {
    int c = ocol0 + n * 16 + lr;
    float bv = bias[c];
#pragma unroll
    for (int f = 0; f < 8; f++) {
      int r0 = orow0 + f * 16 + lk * 4;
#pragma unroll
      for (int j = 0; j < 4; j++) {
        float v = acc[f][n][j] + bv;
        if (OUTF32) v += res[(size_t)(r0 + j) * N + c];
        if (RELU) v = fmaxf(v, 0.f);
        if (OUTF32) outF[(size_t)(r0 + j) * N + c] = v;
        else        outB[(size_t)(r0 + j) * N + c] = f2bf(v);
      }
    }
  }
}

// ---------------- flash attention: register-direct, no LDS, no barriers ----------------
// 2 waves/block (128 thr), QBLK=64, each wave owns 32 q-rows; grid = 16 bh * 32 qt = 512.
// K from KF[bh][d8][key][8] (fragment-major): one contiguous 1KB dwordx4 per mfma.
// V from VF[bh][key8][d][8]. Swapped QK^T (q = lane&31), in-register softmax,
// per-wave causal trip count; verified R4 math/pack/epilogue.
template<int CAUSAL>
__global__ __launch_bounds__(128, 2)
void attn_reg(const u16* __restrict__ Qp, int qstride,
              const u16* __restrict__ KF, const u16* __restrict__ VF,
              u16* __restrict__ O)
{
  int bidx = blockIdx.x;
  int bh = bidx & 15;
  int qt = CAUSAL ? (31 - (bidx >> 4)) : (bidx >> 4);
  int b = bh >> 2, h = bh & 3;
  int tid = threadIdx.x, w = tid >> 6, lane = tid & 63;
  int L = lane & 31, hi = lane >> 5;
  int qbase = qt * 64 + w * 32;

  const u16* qrow = Qp + (size_t)(b * NS + qbase + L) * qstride + h * NDH;
  bf16x8 qf[16];
#pragma unroll
  for (int s = 0; s < 16; s++) qf[s] = ldfrag(qrow + s * 16 + hi * 8);

  const u16* kfb = KF + (size_t)bh * 32 * NS * 8;
  const u16* vfb = VF + (size_t)bh * 256 * 256 * 8;

  f32x16 oacc[8];
#pragma unroll
  for (int db = 0; db < 8; db++) oacc[db] = (f32x16){};
  float m = -1e30f, l = 0.f;

  int nkt = CAUSAL ? (2 * qt + w + 1) : (NS / 32);
  int kdiag = 2 * qt + w;
  constexpr float SC = 1.0f / NDH;

  for (int kt = 0; kt < nkt; kt++) {
    // ---- QK^T (swapped): two independent accumulation chains ----
    f32x16 sa0 = (f32x16){}, sa1 = (f32x16){};
    __builtin_amdgcn_s_setprio(1);
#pragma unroll
    for (int s = 0; s < 16; s++) {
      bf16x8 kf = ldfrag(kfb + ((size_t)(2 * s + hi) * NS + kt * 32 + L) * 8);
      if (s & 1) sa1 = mfma32(kf, qf[s], sa1);
      else       sa0 = mfma32(kf, qf[s], sa0);
    }
    __builtin_amdgcn_s_setprio(0);

    float p[16];
    float tmax = -1e30f;
    bool domask = CAUSAL && (kt == kdiag);
#pragma unroll
    for (int r = 0; r < 16; r++) {
      float v = (sa0[r] + sa1[r]) * SC;
      if (domask) {
        int key = kt * 32 + (r & 3) + 8 * (r >> 2) + 4 * hi;
        if (key > qbase + L) v = -1e30f;
      }
      p[r] = v;
      tmax = fmaxf(tmax, v);
    }
    tmax = fmaxf(tmax, __shfl_xor(tmax, 32));

    float mn = m;
    if (!__all(tmax - m <= 5.0f)) {
      mn = fmaxf(m, tmax);
      float rs = __expf(m - mn);
      m = mn;
      l *= rs;
#pragma unroll
      for (int db = 0; db < 8; db++)
#pragma unroll
        for (int r = 0; r < 16; r++) oacc[db][r] *= rs;
    }
    float psum = 0.f;
#pragma unroll
    for (int r = 0; r < 16; r++) {
      p[r] = __expf(p[r] - mn);
      psum += p[r];
    }
    psum += __shfl_xor(psum, 32);
    l += psum;

    // ---- pack P into PV B-frags (verified) ----
    unsigned pk01 = packbf(p[0], p[1]),  pk23 = packbf(p[2], p[3]);
    unsigned pk45 = packbf(p[4], p[5]),  pk67 = packbf(p[6], p[7]);
    unsigned pk89 = packbf(p[8], p[9]),  pkab = packbf(p[10], p[11]);
    unsigned pkcd = packbf(p[12], p[13]), pkef = packbf(p[14], p[15]);
    unsigned s45 = (unsigned)__shfl_xor((int)pk45, 32);
    unsigned s67 = (unsigned)__shfl_xor((int)pk67, 32);
    unsigned s01 = (unsigned)__shfl_xor((int)pk01, 32);
    unsigned s23 = (unsigned)__shfl_xor((int)pk23, 32);
    unsigned scd = (unsigned)__shfl_xor((int)pkcd, 32);
    unsigned sef = (unsigned)__shfl_xor((int)pkef, 32);
    unsigned s89 = (unsigned)__shfl_xor((int)pk89, 32);
    unsigned sab = (unsigned)__shfl_xor((int)pkab, 32);
    union { unsigned u[4]; bf16x8 v; } fb0, fb1;
    fb0.u[0] = hi ? s45 : pk01;
    fb0.u[1] = hi ? s67 : pk23;
    fb0.u[2] = hi ? pk45 : s01;
    fb0.u[3] = hi ? pk67 : s23;
    fb1.u[0] = hi ? scd : pk89;
    fb1.u[1] = hi ? sef : pkab;
    fb1.u[2] = hi ? pkcd : s89;
    fb1.u[3] = hi ? pkef : sab;
    bf16x8 pb0 = fb0.v, pb1 = fb1.v;

    // ---- PV (O^T): A = V^T fragment direct from global ----
    __builtin_amdgcn_s_setprio(1);
#pragma unroll
    for (int db = 0; db < 8; db++) {
      bf16x8 vf0 = ldfrag(vfb + ((size_t)(kt * 4 + hi) * 256 + db * 32 + L) * 8);
      bf16x8 vf1 = ldfrag(vfb + ((size_t)(kt * 4 + 2 + hi) * 256 + db * 32 + L) * 8);
      oacc[db] = mfma32(vf0, pb0, oacc[db]);
      oacc[db] = mfma32(vf1, pb1, oacc[db]);
    }
    __builtin_amdgcn_s_setprio(0);
  }

  float inv = 1.f / l;
  size_t orow = (size_t)(b * NS + qbase + L) * NE + h * NDH;
#pragma unroll
  for (int db = 0; db < 8; db++) {
#pragma unroll
    for (int rq = 0; rq < 4; rq++) {
      float a0 = oacc[db][rq * 4 + 0] * inv, a1 = oacc[db][rq * 4 + 1] * inv;
      float a2 = oacc[db][rq * 4 + 2] * inv, a3 = oacc[db][rq * 4 + 3] * inv;
      uint2 wv;
      wv.x = packbf(a0, a1);
      wv.y = packbf(a2, a3);
      *(uint2*)&O[orow + db * 32 + rq * 8 + hi * 4] = wv;
    }
  }
}

// ---------------- LayerNorm (eps=1e-3), optional relu, optional bf16 copy ----------------
template<int RELU, int WBF>
__global__ __launch_bounds__(256)
void ln_kernel(const float* __restrict__ x, const float* __restrict__ g,
               const float* __restrict__ bb, float* __restrict__ outF,
               u16* __restrict__ outB)
{
  int row = blockIdx.x, tid = threadIdx.x;
  float4 v = ((const float4*)(x + (size_t)row * NE))[tid];
  float s = v.x + v.y + v.z + v.w;
  float s2 = v.x * v.x + v.y * v.y + v.z * v.z + v.w * v.w;
#pragma unroll
  for (int off = 32; off; off >>= 1) {
    s += __shfl_xor(s, off);
    s2 += __shfl_xor(s2, off);
  }
  __shared__ float red[8];
  int wid = tid >> 6, lane = tid & 63;
  if (lane == 0) { red[wid] = s; red[4 + wid] = s2; }
  __syncthreads();
  s = red[0] + red[1] + red[2] + red[3];
  s2 = red[4] + red[5] + red[6] + red[7];
  float mean = s * (1.f / NE);
  float var = s2 * (1.f / NE) - mean * mean;
  float rstd = rsqrtf(var + 1e-3f);
  float4 gg = ((const float4*)g)[tid];
  float4 bv = ((const float4*)bb)[tid];
  float4 o;
  o.x = (v.x - mean) * rstd * gg.x + bv.x;
  o.y = (v.y - mean) * rstd * gg.y + bv.y;
  o.z = (v.z - mean) * rstd * gg.z + bv.z;
  o.w = (v.w - mean) * rstd * gg.w + bv.w;
  if (RELU) {
    o.x = fmaxf(o.x, 0.f); o.y = fmaxf(o.y, 0.f);
    o.z = fmaxf(o.z, 0.f); o.w = fmaxf(o.w, 0.f);
  }
  ((float4*)(outF + (size_t)row * NE))[tid] = o;
  if (WBF) {
    ushort4 ob;
    ob.x = f2bf(o.x); ob.y = f2bf(o.y); ob.z = f2bf(o.z); ob.w = f2bf(o.w);
    ((ushort4*)(outB + (size_t)row * NE))[tid] = ob;
  }
}

// ---------------- workspace layout (bytes) ----------------
constexpr size_t OFF_X    = 0;                       // 16 MB: Xbf -> O1 -> Ctxbf -> O2
constexpr size_t OFF_W    = OFF_X + 16777216;        // 32 MB packed weights
constexpr size_t OFF_BIAS = OFF_W + 33554432;        // packed biases
constexpr size_t OFF_QKV  = OFF_BIAS + 32768;        // 48 MB QKV1 / (KV2 + Q2) / MID
constexpr size_t OFF_VT   = OFF_QKV + 50331648;      // 16 MB VF (fragment-major V)
constexpr size_t OFF_T0   = OFF_VT + 16777216;       // 32 MB f32 scratch; KF aliases here
constexpr size_t OFF_A    = OFF_T0 + 33554432;       // 32 MB f32 a / c
constexpr size_t OFF_ABF  = OFF_A + 33554432;        // 16 MB bf16 a / c

extern "C" void kernel_launch(void* const* d_in, const int* in_sizes, int n_in,
                              void* d_out, int out_size, void* d_ws, size_t ws_size,
                              hipStream_t stream) {
  (void)in_sizes; (void)n_in; (void)out_size; (void)ws_size;
  const float* inp = (const float*)d_in[0];
  const float* ctx = (const float*)d_in[1];
  const float* Wk1 = (const float*)d_in[2];  const float* bk1 = (const float*)d_in[3];
  const float* Wq1 = (const float*)d_in[4];  const float* bq1 = (const float*)d_in[5];
  const float* Wv1 = (const float*)d_in[6];  const float* bv1 = (const float*)d_in[7];
  const float* Wo1 = (const float*)d_in[8];  const float* bo1 = (const float*)d_in[9];
  const float* Wk2 = (const float*)d_in[10]; const float* bk2 = (const float*)d_in[11];
  const float* Wq2 = (const float*)d_in[12]; const float* bq2 = (const float*)d_in[13];
  const float* Wv2 = (const float*)d_in[14]; const float* bv2 = (const float*)d_in[15];
  const float* Wo2 = (const float*)d_in[16]; const float* bo2 = (const float*)d_in[17];
  const float* lng = (const float*)d_in[18]; const float* lnb = (const float*)d_in[19];
  const float* W1  = (const float*)d_in[20]; const float* b1  = (const float*)d_in[21];
  const float* W2  = (const float*)d_in[22]; const float* b2  = (const float*)d_in[23];
  float* out = (float*)d_out;
  char* ws = (char*)d_ws;

  u16* XBF    = (u16*)(ws + OFF_X);
  u16* WQKV1T = (u16*)(ws + OFF_W);
  u16* WKV2T  = WQKV1T + 3072 * 1024;
  u16* WQ2T   = WKV2T + 2048 * 1024;
  u16* WO1T   = WQ2T + 1024 * 1024;
  u16* WO2T   = WO1T + 1024 * 1024;
  u16* W1T    = WO2T + 1024 * 1024;
  u16* W2T    = W1T + 4096 * 1024;
  float* BQKV1 = (float*)(ws + OFF_BIAS);
  float* BKV2  = BQKV1 + 3072;
  u16* QKV  = (u16*)(ws + OFF_QKV);
  u16* Q2   = QKV + 8192 * 2048;
  u16* VF   = (u16*)(ws + OFF_VT);         // [16][256][256][8] fragment-major V
  u16* MID  = QKV;
  float* T0 = (float*)(ws + OFF_T0);
  u16* KF   = (u16*)T0;                    // [16][32][2048][8] fragment-major K (aliases T0)
  float* Af = (float*)(ws + OFF_A);
  u16* ABF  = (u16*)(ws + OFF_ABF);
  u16* Obuf = XBF;

  dim3 tb(32, 8);

  // input cast + weight/bias packing
  cast_f32_bf16<<<8192, 256, 0, stream>>>(inp, XBF, NR * NE / 4);
  transpose_cast<<<dim3(8, 32, 4), tb, 0, stream>>>(Wk1, WQKV1T,               NE, NDH);
  transpose_cast<<<dim3(8, 32, 4), tb, 0, stream>>>(Wq1, WQKV1T + 1024 * 1024, NE, NDH);
  transpose_cast<<<dim3(8, 32, 4), tb, 0, stream>>>(Wv1, WQKV1T + 2048 * 1024, NE, NDH);
  transpose_cast<<<dim3(32, 32, 1), tb, 0, stream>>>(Wo1, WO1T, NE, NE);
  transpose_cast<<<dim3(8, 32, 4), tb, 0, stream>>>(Wk2, WKV2T,               NE, NDH);
  transpose_cast<<<dim3(8, 32, 4), tb, 0, stream>>>(Wv2, WKV2T + 1024 * 1024, NE, NDH);
  transpose_cast<<<dim3(8, 32, 4), tb, 0, stream>>>(Wq2, WQ2T, NE, NDH);
  transpose_cast<<<dim3(32, 32, 1), tb, 0, stream>>>(Wo2, WO2T, NE, NE);
  transpose_cast<<<dim3(128, 32, 1), tb, 0, stream>>>(W1, W1T, NE, NF);
  transpose_cast<<<dim3(32, 128, 1), tb, 0, stream>>>(W2, W2T, NF, NE);
  copy_f32<<<4, 256, 0, stream>>>(bk1, BQKV1, 1024);
  copy_f32<<<4, 256, 0, stream>>>(bq1, BQKV1 + 1024, 1024);
  copy_f32<<<4, 256, 0, stream>>>(bv1, BQKV1 + 2048, 1024);
  copy_f32<<<4, 256, 0, stream>>>(bk2, BKV2, 1024);
  copy_f32<<<4, 256, 0, stream>>>(bv2, BKV2 + 1024, 1024);

  // ---- self-attention block ----
  gemm4r<256, 0, 0><<<dim3(12, 32), 512, 0, stream>>>(XBF, WQKV1T, BQKV1, nullptr,
                                                      nullptr, QKV, NR, 3072, NE);
  repack_k<<<dim3(64, 8, 16), tb, 0, stream>>>(QKV, 3072, KF);
  repack_v<<<dim3(64, 8, 16), tb, 0, stream>>>(QKV + 2048, 3072, VF);
  attn_reg<1><<<512, 128, 0, stream>>>(QKV + 1024, 3072, KF, VF, Obuf);
  gemm4r<128, 1, 0><<<dim3(8, 32), 512, 0, stream>>>(Obuf, WO1T, bo1, inp,
                                                     T0, nullptr, NR, NE, NE);
  ln_kernel<0, 1><<<NR, 256, 0, stream>>>(T0, lng, lnb, Af, ABF);

  // ---- cross-attention block ----
  cast_f32_bf16<<<8192, 256, 0, stream>>>(ctx, XBF, NR * NE / 4);
  gemm4r<256, 0, 0><<<dim3(8, 32), 512, 0, stream>>>(XBF, WKV2T, BKV2, nullptr,
                                                     nullptr, QKV, NR, 2048, NE);
  gemm4r<128, 0, 0><<<dim3(8, 32), 512, 0, stream>>>(ABF, WQ2T, bq2, nullptr,
                                                     nullptr, Q2, NR, NE, NE);
  repack_k<<<dim3(64, 8, 16), tb, 0, stream>>>(QKV, 2048, KF);
  repack_v<<<dim3(64, 8, 16), tb, 0, stream>>>(QKV + 1024, 2048, VF);
  attn_reg<0><<<512, 128, 0, stream>>>(Q2, 1024, KF, VF, Obuf);
  gemm4r<128, 1, 0><<<dim3(8, 32), 512, 0, stream>>>(Obuf, WO2T, bo2, Af,
                                                     T0, nullptr, NR, NE, NE);
  ln_kernel<0, 1><<<NR, 256, 0, stream>>>(T0, lng, lnb, Af, ABF);

  // ---- FFN ----
  gemm4r<256, 0, 1><<<dim3(16, 32), 512, 0, stream>>>(ABF, W1T, b1, nullptr,
                                                      nullptr, MID, NR, NF, NE);
  gemm4r<128, 1, 0><<<dim3(8, 32), 512, 0, stream>>>(MID, W2T, b2, Af,
                                                     T0, nullptr, NR, NE, NF);
  ln_kernel<1, 0><<<NR, 256, 0, stream>>>(T0, lng, lnb, out, nullptr);
}

// Round 10
// 762.317 us; speedup vs baseline: 1.7379x; 1.7379x over previous
//
#include <hip/hip_runtime.h>

#define DEV __device__ __forceinline__

typedef unsigned short u16;
typedef __bf16 bf16x8 __attribute__((ext_vector_type(8)));
typedef bf16x8 __attribute__((may_alias)) bf16x8a;
typedef float f32x4 __attribute__((ext_vector_type(4)));
typedef float f32x16 __attribute__((ext_vector_type(16)));

constexpr int NB = 4, NS = 2048, NE = 1024, NH = 4, NDH = 256, NF = 4096;
constexpr int NR = NB * NS;  // 8192 rows

DEV u16 f2bf(float f) {
  unsigned u = __float_as_uint(f);
  u += 0x7fff + ((u >> 16) & 1);
  return (u16)(u >> 16);
}

DEV f32x4 mfma16(bf16x8 a, bf16x8 b, f32x4 c) {
  return __builtin_amdgcn_mfma_f32_16x16x32_bf16(a, b, c, 0, 0, 0);
}
DEV f32x16 mfma32(bf16x8 a, bf16x8 b, f32x16 c) {
  return __builtin_amdgcn_mfma_f32_32x32x16_bf16(a, b, c, 0, 0, 0);
}

DEV bf16x8 ldfrag(const u16* p) { return *(const bf16x8a*)p; }

DEV void gload_lds16(const void* g, void* l) {
  __builtin_amdgcn_global_load_lds(
      (const __attribute__((address_space(1))) void*)g,
      (__attribute__((address_space(3))) void*)l, 16, 0, 0);
}

DEV void blockbar() {
  asm volatile("" ::: "memory");
  __builtin_amdgcn_s_barrier();
  asm volatile("" ::: "memory");
}

DEV unsigned packbf(float a, float b) {
  union { __bf16 h[2]; unsigned u; } x;
  x.h[0] = (__bf16)a; x.h[1] = (__bf16)b;
  return x.u;
}

// ---------------- elementwise cast f32 -> bf16 ----------------
__global__ void cast_f32_bf16(const float* __restrict__ in, u16* __restrict__ out, int n4) {
  int i = blockIdx.x * 256 + threadIdx.x;
  if (i >= n4) return;
  float4 v = ((const float4*)in)[i];
  ushort4 o;
  o.x = f2bf(v.x); o.y = f2bf(v.y); o.z = f2bf(v.z); o.w = f2bf(v.w);
  ((ushort4*)out)[i] = o;
}

// ---------------- batched transpose + cast: in[z][R][C] f32 -> out[z][C][R] bf16 ----------------
__global__ void transpose_cast(const float* __restrict__ in, u16* __restrict__ out, int R, int C) {
  __shared__ float t[32][33];
  size_t base = (size_t)blockIdx.z * R * C;
  int c0 = blockIdx.x * 32, r0 = blockIdx.y * 32;
  int x = threadIdx.x;
  for (int yy = threadIdx.y; yy < 32; yy += 8)
    t[yy][x] = in[base + (size_t)(r0 + yy) * C + c0 + x];
  __syncthreads();
  for (int yy = threadIdx.y; yy < 32; yy += 8)
    out[base + (size_t)(c0 + yy) * R + r0 + x] = f2bf(t[x][yy]);
}

// ---------------- V transpose: V[(b*S+s)*vstride + h*DH + d] -> Vt[(bh*DH+d)*S + s] ----------------
__global__ void transpose_v(const u16* __restrict__ V, int vstride, u16* __restrict__ Vt) {
  __shared__ u16 t[32][34];
  int bh = blockIdx.z, b = bh >> 2, h = bh & (NH - 1);
  int s0 = blockIdx.x * 32, d0 = blockIdx.y * 32;
  int x = threadIdx.x;
  for (int yy = threadIdx.y; yy < 32; yy += 8)
    t[yy][x] = V[(size_t)(b * NS + s0 + yy) * vstride + h * NDH + d0 + x];
  __syncthreads();
  for (int yy = threadIdx.y; yy < 32; yy += 8)
    Vt[((size_t)bh * NDH + d0 + yy) * NS + s0 + x] = t[x][yy];
}

// ---------------- small f32 copy (bias packing) ----------------
__global__ void copy_f32(const float* __restrict__ s, float* __restrict__ d, int n) {
  int i = blockIdx.x * 256 + threadIdx.x;
  if (i < n) d[i] = s[i];
}

// ---------------- 8-phase GEMM: C[M,N] = A[M,K] * Bt[N,K]^T (+bias,+res,relu) ----------------
// (R6 version - best measured GEMM total)
template<int BN, int OUTF32, int RELU>
__global__ __launch_bounds__(512, 1)
void gemm8p(const u16* __restrict__ A, const u16* __restrict__ Bt,
            const float* __restrict__ bias, const float* __restrict__ res,
            float* __restrict__ outF, u16* __restrict__ outB,
            int M, int N, int K)
{
  constexpr int NFRAG = BN / 64;          // n-frags per wave (4 or 2)
  __shared__ __align__(16) u16 smem[32768 + 2 * BN * 64];   // A: [2][256][64]; B: [2][BN][64]

  int tid = threadIdx.x, w = tid >> 6, lane = tid & 63;
  int lr = lane & 15, lk = lane >> 4;
  int wm = w >> 2, wn = w & 3;

  int flat = blockIdx.y * gridDim.x + blockIdx.x;
  int cpx = (gridDim.x * gridDim.y) >> 3;
  int swz = (flat & 7) * cpx + (flat >> 3);
  int bx = swz % gridDim.x, by = swz / gridDim.x;
  int rowBlk = by * 256, colBlk = bx * BN;

  f32x4 acc[8][NFRAG];
#pragma unroll
  for (int f = 0; f < 8; f++)
#pragma unroll
    for (int n = 0; n < NFRAG; n++) acc[f][n] = (f32x4){0.f, 0.f, 0.f, 0.f};

  int srow = lane >> 3;                    // 0..7 within 8-row group
  int scol = ((lane & 7) ^ (srow & 7)) * 8;  // pre-swizzled source granule

  const u16* gA = A + (size_t)rowBlk * K;
  const u16* gB = Bt + (size_t)colBlk * K;

  auto stageA = [&](int t, int p, int h) {
#pragma unroll
    for (int j = 0; j < 2; j++) {
      int rbase = h * 128 + (w * 2 + j) * 8;
      gload_lds16(gA + (size_t)(rbase + srow) * K + t * 64 + scol,
                  &smem[(p * 256 + rbase) * 64]);
    }
  };
  auto stageB = [&](int t, int p, int h) {
#pragma unroll
    for (int j = 0; j < 2; j++) {
      int rbase = h * 128 + (w * 2 + j) * 8;
      gload_lds16(gB + (size_t)(rbase + srow) * K + t * 64 + scol,
                  &smem[32768 + (p * BN + rbase) * 64]);
    }
  };

  // prologue: stage tile 0 into buf 0
  stageB(0, 0, 0);
  if (BN == 256) stageB(0, 0, 1);
  stageA(0, 0, 0);
  stageA(0, 0, 1);
  asm volatile("s_waitcnt vmcnt(0)" ::: "memory");
  blockbar();

  int NT = K >> 6;
  for (int t = 0; t < NT; t++) {
    int p = t & 1;
    bool pre = (t + 1 < NT);
    bf16x8 bf[NFRAG][2];
#pragma unroll
    for (int q = 0; q < 4; q++) {
      if (q == 0) {
#pragma unroll
        for (int n = 0; n < NFRAG; n++)
#pragma unroll
          for (int s = 0; s < 2; s++) {
            int rowB = wn * (BN >> 2) + n * 16 + lr;
            bf[n][s] = ldfrag(&smem[32768 + (p * BN + rowB) * 64 +
                                    (((s * 4 + lk) ^ (lr & 7)) * 8)]);
          }
      }
      bf16x8 af[2][2];
#pragma unroll
      for (int i = 0; i < 2; i++)
#pragma unroll
        for (int s = 0; s < 2; s++) {
          int rowA = wm * 128 + (q * 2 + i) * 16 + lr;
          af[i][s] = ldfrag(&smem[(p * 256 + rowA) * 64 +
                                  (((s * 4 + lk) ^ (lr & 7)) * 8)]);
        }
      if (pre) {
        if (BN == 256) {
          if (q == 0) { stageB(t + 1, p ^ 1, 0); stageB(t + 1, p ^ 1, 1); }
          else if (q == 1) stageA(t + 1, p ^ 1, 0);
          else if (q == 2) stageA(t + 1, p ^ 1, 1);
        } else {
          if (q == 0) stageB(t + 1, p ^ 1, 0);
          else if (q == 1) stageA(t + 1, p ^ 1, 0);
          else if (q == 2) stageA(t + 1, p ^ 1, 1);
        }
      }
      blockbar();
      asm volatile("s_waitcnt lgkmcnt(0)" ::: "memory");
      __builtin_amdgcn_s_setprio(1);
#pragma unroll
      for (int i = 0; i < 2; i++)
#pragma unroll
        for (int n = 0; n < NFRAG; n++)
#pragma unroll
          for (int s = 0; s < 2; s++)
            acc[q * 2 + i][n] = mfma16(af[i][s], bf[n][s], acc[q * 2 + i][n]);
      __builtin_amdgcn_s_setprio(0);
      if (q == 3) asm volatile("s_waitcnt vmcnt(0)" ::: "memory");
      blockbar();
    }
  }

  int orow0 = rowBlk + wm * 128;
  int ocol0 = colBlk + wn * (BN >> 2);
#pragma unroll
  for (int n = 0; n < NFRAG; n++) {
    int c = ocol0 + n * 16 + lr;
    float bv = bias[c];
#pragma unroll
    for (int f = 0; f < 8; f++) {
      int r0 = orow0 + f * 16 + lk * 4;
#pragma unroll
      for (int j = 0; j < 4; j++) {
        float v = acc[f][n][j] + bv;
        if (OUTF32) v += res[(size_t)(r0 + j) * N + c];
        if (RELU) v = fmaxf(v, 0.f);
        if (OUTF32) outF[(size_t)(r0 + j) * N + c] = v;
        else        outB[(size_t)(r0 + j) * N + c] = f2bf(v);
      }
    }
  }
}

// ---------------- flash attention: 4 waves, QBLK=64, KBLK=64, split-K pairs ----
// grid 512 = 16 bh * 32 qtiles; LDS 64KB (single-buffered K 32KB + V 32KB) ->
// 2 blocks/CU co-resident. 4-barrier rotation per tile with counted vmcnt.
// FIX vs R9: prologue drains vmcnt(0) (stage-group ordering across the two
// builtin groups is NOT guaranteed without an asm clobber between them; counted
// vmcnt(8) was unsafe). All loop groups are clobber-separated -> counts exact.
template<int CAUSAL>
__global__ __launch_bounds__(256, 2)
void attn4w(const u16* __restrict__ Qp, int qstride,
            const u16* __restrict__ Kp, int kstride,
            const u16* __restrict__ Vt, u16* __restrict__ O)
{
  __shared__ __align__(16) u16 smem[32768];   // 64KB: lK [64][256], lV [256][64]

  int bidx = blockIdx.x;
  int bh = bidx & 15;
  int qt = CAUSAL ? (31 - (bidx >> 4)) : (bidx >> 4);
  int b = bh >> 2, h = bh & 3;
  int tid = threadIdx.x, w = tid >> 6, lane = tid & 63;
  int L = lane & 31, hi = lane >> 5;
  int g = w >> 1, ks = w & 1;

  int qbase = qt * 64 + g * 32;

  const u16* qrow = Qp + (size_t)(b * NS + qbase + L) * qstride + h * NDH;
  bf16x8 qf[16];
#pragma unroll
  for (int s = 0; s < 16; s++) qf[s] = ldfrag(qrow + s * 16 + hi * 8);

  f32x16 oacc[8];
#pragma unroll
  for (int db = 0; db < 8; db++) oacc[db] = (f32x16){};
  float m = -1e30f, l = 0.f;

  int nkt = CAUSAL ? (qt + 1) : (NS / 64);
  constexpr float SC = 1.0f / NDH;

  const u16* kbase = Kp + (size_t)(b * NS) * kstride + h * NDH;
  const u16* vbase = Vt + (size_t)bh * NDH * NS;

  auto stageK = [&](int kt) {
#pragma unroll
    for (int ii = 0; ii < 8; ii++) {
      int gi = w * 8 + ii;                       // 0..31
      int krow = 2 * gi + hi;
      int kcol = L ^ (krow & 31);
      gload_lds16(kbase + (size_t)(kt * 64 + krow) * kstride + kcol * 8,
                  &smem[gi * 512]);
    }
  };
  auto stageV = [&](int kt) {
#pragma unroll
    for (int ii = 0; ii < 8; ii++) {
      int gi = w * 8 + ii;
      int vd = gi * 8 + (lane >> 3);
      int vg = (lane & 7) ^ (vd & 7);
      gload_lds16(vbase + (size_t)vd * NS + kt * 64 + vg * 8,
                  &smem[16384 + gi * 512]);
    }
  };

  stageK(0);
  asm volatile("" ::: "memory");
  stageV(0);
  asm volatile("s_waitcnt vmcnt(0)" ::: "memory");   // FIX: full drain (ordering-safe)
  blockbar();

  for (int kt = 0; kt < nkt; kt++) {
    bool last = (kt + 1 == nkt);
    int ksub0 = kt * 64 + ks * 32;
    bool skip = CAUSAL && (ksub0 > qbase + 31);
    bool domask = CAUSAL && !skip && (ksub0 + 31 > qbase);

    // ---- QK^T (swapped): col = q = L, rows = our 32-key subtile ----
    f32x16 sa = (f32x16){};
    if (!skip) {
      __builtin_amdgcn_s_setprio(1);
#pragma unroll
      for (int s = 0; s < 16; s++) {
        int row = ks * 32 + L;
        bf16x8 kf = ldfrag(&smem[row * 256 + (((2 * s + hi) ^ L) & 31) * 8]);
        sa = mfma32(kf, qf[s], sa);
      }
      __builtin_amdgcn_s_setprio(0);
    }
    blockbar();                                  // lK free
    if (!last) stageK(kt + 1);                   // K latency hides under softmax

    bf16x8 pb0, pb1;
    if (!skip) {
      float p[16];
      float tmax = -1e30f;
#pragma unroll
      for (int r = 0; r < 16; r++) {
        float v = sa[r] * SC;
        if (domask) {
          int key = ksub0 + (r & 3) + 8 * (r >> 2) + 4 * hi;
          if (key > qbase + L) v = -1e30f;
        }
        p[r] = v;
        tmax = fmaxf(tmax, v);
      }
      tmax = fmaxf(tmax, __shfl_xor(tmax, 32));

      float mn = m;
      if (!__all(tmax - m <= 5.0f)) {
        mn = fmaxf(m, tmax);
        float rs = __expf(m - mn);
        m = mn;
        l *= rs;
#pragma unroll
        for (int db = 0; db < 8; db++)
#pragma unroll
          for (int r = 0; r < 16; r++) oacc[db][r] *= rs;
      }
      float psum = 0.f;
#pragma unroll
      for (int r = 0; r < 16; r++) {
        p[r] = __expf(p[r] - mn);
        psum += p[r];
      }
      psum += __shfl_xor(psum, 32);
      l += psum;

      unsigned pk01 = packbf(p[0], p[1]),  pk23 = packbf(p[2], p[3]);
      unsigned pk45 = packbf(p[4], p[5]),  pk67 = packbf(p[6], p[7]);
      unsigned pk89 = packbf(p[8], p[9]),  pkab = packbf(p[10], p[11]);
      unsigned pkcd = packbf(p[12], p[13]), pkef = packbf(p[14], p[15]);
      unsigned s45 = (unsigned)__shfl_xor((int)pk45, 32);
      unsigned s67 = (unsigned)__shfl_xor((int)pk67, 32);
      unsigned s01 = (unsigned)__shfl_xor((int)pk01, 32);
      unsigned s23 = (unsigned)__shfl_xor((int)pk23, 32);
      unsigned scd = (unsigned)__shfl_xor((int)pkcd, 32);
      unsigned sef = (unsigned)__shfl_xor((int)pkef, 32);
      unsigned s89 = (unsigned)__shfl_xor((int)pk89, 32);
      unsigned sab = (unsigned)__shfl_xor((int)pkab, 32);
      union { unsigned u[4]; bf16x8 v; } fb0, fb1;
      fb0.u[0] = hi ? s45 : pk01;
      fb0.u[1] = hi ? s67 : pk23;
      fb0.u[2] = hi ? pk45 : s01;
      fb0.u[3] = hi ? pk67 : s23;
      fb1.u[0] = hi ? scd : pk89;
      fb1.u[1] = hi ? sef : pkab;
      fb1.u[2] = hi ? pkcd : s89;
      fb1.u[3] = hi ? pkef : sab;
      pb0 = fb0.v; pb1 = fb1.v;
    }

    if (!last) asm volatile("s_waitcnt vmcnt(8)" ::: "memory");  // V(kt) ready
    else       asm volatile("s_waitcnt vmcnt(0)" ::: "memory");
    blockbar();

    if (!skip) {
      __builtin_amdgcn_s_setprio(1);
#pragma unroll
      for (int db = 0; db < 8; db++) {
        int vd = db * 32 + L;
        bf16x8 vf0 = ldfrag(&smem[16384 + vd * 64 + (((ks * 4 + hi) ^ (vd & 7)) & 7) * 8]);
        bf16x8 vf1 = ldfrag(&smem[16384 + vd * 64 + (((ks * 4 + 2 + hi) ^ (vd & 7)) & 7) * 8]);
        oacc[db] = mfma32(vf0, pb0, oacc[db]);
        oacc[db] = mfma32(vf1, pb1, oacc[db]);
      }
      __builtin_amdgcn_s_setprio(0);
    }
    blockbar();                                  // lV free
    if (!last) {
      stageV(kt + 1);
      asm volatile("s_waitcnt vmcnt(8)" ::: "memory");  // K(kt+1) ready
      blockbar();
    }
  }

  // ---- merge wave pairs (w, w^1): disjoint keys, same 32 q-rows ----
  float* fsm = (float*)smem;
  blockbar();
  if (hi == 0) { fsm[w * 64 + L * 2] = m; fsm[w * 64 + L * 2 + 1] = l; }
  asm volatile("s_waitcnt lgkmcnt(0)" ::: "memory");
  blockbar();
  float mb = fsm[(w ^ 1) * 64 + L * 2];
  float lb = fsm[(w ^ 1) * 64 + L * 2 + 1];
  float M = fmaxf(m, mb);
  float eo = __expf(m - M);
  float lt = l * eo + lb * __expf(mb - M);
  asm volatile("s_waitcnt lgkmcnt(0)" ::: "memory");
  blockbar();
  float* reg = fsm + g * 8192;   // 32KB region per pair: [256 d][32 q] f32
  if (w & 1) {
#pragma unroll
    for (int db = 0; db < 8; db++)
#pragma unroll
      for (int r = 0; r < 16; r++) {
        int d = db * 32 + (r & 3) + 8 * (r >> 2) + 4 * hi;
        reg[d * 32 + L] = oacc[db][r] * eo;
      }
  }
  asm volatile("s_waitcnt lgkmcnt(0)" ::: "memory");
  blockbar();
  if (!(w & 1)) {
    float inv = 1.f / lt;
    size_t orow = (size_t)(b * NS + qbase + L) * NE + h * NDH;
#pragma unroll
    for (int db = 0; db < 8; db++) {
#pragma unroll
      for (int rq = 0; rq < 4; rq++) {
        int d0 = db * 32 + rq * 8 + hi * 4;
        float a0 = (oacc[db][rq * 4 + 0] * eo + reg[(d0 + 0) * 32 + L]) * inv;
        float a1 = (oacc[db][rq * 4 + 1] * eo + reg[(d0 + 1) * 32 + L]) * inv;
        float a2 = (oacc[db][rq * 4 + 2] * eo + reg[(d0 + 2) * 32 + L]) * inv;
        float a3 = (oacc[db][rq * 4 + 3] * eo + reg[(d0 + 3) * 32 + L]) * inv;
        uint2 wv;
        wv.x = packbf(a0, a1);
        wv.y = packbf(a2, a3);
        *(uint2*)&O[orow + d0] = wv;
      }
    }
  }
}

// ---------------- LayerNorm (eps=1e-3), optional relu, optional bf16 copy ----------------
template<int RELU, int WBF>
__global__ __launch_bounds__(256)
void ln_kernel(const float* __restrict__ x, const float* __restrict__ g,
               const float* __restrict__ bb, float* __restrict__ outF,
               u16* __restrict__ outB)
{
  int row = blockIdx.x, tid = threadIdx.x;
  float4 v = ((const float4*)(x + (size_t)row * NE))[tid];
  float s = v.x + v.y + v.z + v.w;
  float s2 = v.x * v.x + v.y * v.y + v.z * v.z + v.w * v.w;
#pragma unroll
  for (int off = 32; off; off >>= 1) {
    s += __shfl_xor(s, off);
    s2 += __shfl_xor(s2, off);
  }
  __shared__ float red[8];
  int wid = tid >> 6, lane = tid & 63;
  if (lane == 0) { red[wid] = s; red[4 + wid] = s2; }
  __syncthreads();
  s = red[0] + red[1] + red[2] + red[3];
  s2 = red[4] + red[5] + red[6] + red[7];
  float mean = s * (1.f / NE);
  float var = s2 * (1.f / NE) - mean * mean;
  float rstd = rsqrtf(var + 1e-3f);
  float4 gg = ((const float4*)g)[tid];
  float4 bv = ((const float4*)bb)[tid];
  float4 o;
  o.x = (v.x - mean) * rstd * gg.x + bv.x;
  o.y = (v.y - mean) * rstd * gg.y + bv.y;
  o.z = (v.z - mean) * rstd * gg.z + bv.z;
  o.w = (v.w - mean) * rstd * gg.w + bv.w;
  if (RELU) {
    o.x = fmaxf(o.x, 0.f); o.y = fmaxf(o.y, 0.f);
    o.z = fmaxf(o.z, 0.f); o.w = fmaxf(o.w, 0.f);
  }
  ((float4*)(outF + (size_t)row * NE))[tid] = o;
  if (WBF) {
    ushort4 ob;
    ob.x = f2bf(o.x); ob.y = f2bf(o.y); ob.z = f2bf(o.z); ob.w = f2bf(o.w);
    ((ushort4*)(outB + (size_t)row * NE))[tid] = ob;
  }
}

// ---------------- workspace layout (bytes) ----------------
constexpr size_t OFF_X    = 0;                       // 16 MB: Xbf -> O1 -> Ctxbf -> O2
constexpr size_t OFF_W    = OFF_X + 16777216;        // 32 MB packed weights
constexpr size_t OFF_BIAS = OFF_W + 33554432;        // packed biases
constexpr size_t OFF_QKV  = OFF_BIAS + 32768;        // 48 MB QKV1 / (KV2 + Q2) / MID
constexpr size_t OFF_VT   = OFF_QKV + 50331648;      // 16 MB Vt
constexpr size_t OFF_T0   = OFF_VT + 16777216;       // 32 MB f32 scratch (pre-LN)
constexpr size_t OFF_A    = OFF_T0 + 33554432;       // 32 MB f32 a / c
constexpr size_t OFF_ABF  = OFF_A + 33554432;        // 16 MB bf16 a / c

extern "C" void kernel_launch(void* const* d_in, const int* in_sizes, int n_in,
                              void* d_out, int out_size, void* d_ws, size_t ws_size,
                              hipStream_t stream) {
  (void)in_sizes; (void)n_in; (void)out_size; (void)ws_size;
  const float* inp = (const float*)d_in[0];
  const float* ctx = (const float*)d_in[1];
  const float* Wk1 = (const float*)d_in[2];  const float* bk1 = (const float*)d_in[3];
  const float* Wq1 = (const float*)d_in[4];  const float* bq1 = (const float*)d_in[5];
  const float* Wv1 = (const float*)d_in[6];  const float* bv1 = (const float*)d_in[7];
  const float* Wo1 = (const float*)d_in[8];  const float* bo1 = (const float*)d_in[9];
  const float* Wk2 = (const float*)d_in[10]; const float* bk2 = (const float*)d_in[11];
  const float* Wq2 = (const float*)d_in[12]; const float* bq2 = (const float*)d_in[13];
  const float* Wv2 = (const float*)d_in[14]; const float* bv2 = (const float*)d_in[15];
  const float* Wo2 = (const float*)d_in[16]; const float* bo2 = (const float*)d_in[17];
  const float* lng = (const float*)d_in[18]; const float* lnb = (const float*)d_in[19];
  const float* W1  = (const float*)d_in[20]; const float* b1  = (const float*)d_in[21];
  const float* W2  = (const float*)d_in[22]; const float* b2  = (const float*)d_in[23];
  float* out = (float*)d_out;
  char* ws = (char*)d_ws;

  u16* XBF    = (u16*)(ws + OFF_X);        // also ctx-bf16 and attention-O buffer
  u16* WQKV1T = (u16*)(ws + OFF_W);        // rows [K|Q|V] x 1024
  u16* WKV2T  = WQKV1T + 3072 * 1024;      // rows [K|V] x 1024
  u16* WQ2T   = WKV2T + 2048 * 1024;
  u16* WO1T   = WQ2T + 1024 * 1024;
  u16* WO2T   = WO1T + 1024 * 1024;
  u16* W1T    = WO2T + 1024 * 1024;        // [4096][1024]
  u16* W2T    = W1T + 4096 * 1024;         // [1024][4096]
  float* BQKV1 = (float*)(ws + OFF_BIAS);  // 3072
  float* BKV2  = BQKV1 + 3072;             // 2048
  u16* QKV  = (u16*)(ws + OFF_QKV);        // [8192][3072] (self) / [8192][2048] KV2
  u16* Q2   = QKV + 8192 * 2048;           // [8192][1024]
  u16* VT   = (u16*)(ws + OFF_VT);         // [16][256][2048]
  u16* MID  = QKV;                         // [8192][4096] (aliases QKV+VT, both dead)
  float* T0 = (float*)(ws + OFF_T0);
  float* Af = (float*)(ws + OFF_A);
  u16* ABF  = (u16*)(ws + OFF_ABF);
  u16* Obuf = XBF;

  dim3 tb(32, 8);

  // input cast + weight/bias packing
  cast_f32_bf16<<<8192, 256, 0, stream>>>(inp, XBF, NR * NE / 4);
  transpose_cast<<<dim3(8, 32, 4), tb, 0, stream>>>(Wk1, WQKV1T,               NE, NDH);
  transpose_cast<<<dim3(8, 32, 4), tb, 0, stream>>>(Wq1, WQKV1T + 1024 * 1024, NE, NDH);
  transpose_cast<<<dim3(8, 32, 4), tb, 0, stream>>>(Wv1, WQKV1T + 2048 * 1024, NE, NDH);
  transpose_cast<<<dim3(32, 32, 1), tb, 0, stream>>>(Wo1, WO1T, NE, NE);
  transpose_cast<<<dim3(8, 32, 4), tb, 0, stream>>>(Wk2, WKV2T,               NE, NDH);
  transpose_cast<<<dim3(8, 32, 4), tb, 0, stream>>>(Wv2, WKV2T + 1024 * 1024, NE, NDH);
  transpose_cast<<<dim3(8, 32, 4), tb, 0, stream>>>(Wq2, WQ2T, NE, NDH);
  transpose_cast<<<dim3(32, 32, 1), tb, 0, stream>>>(Wo2, WO2T, NE, NE);
  transpose_cast<<<dim3(128, 32, 1), tb, 0, stream>>>(W1, W1T, NE, NF);
  transpose_cast<<<dim3(32, 128, 1), tb, 0, stream>>>(W2, W2T, NF, NE);
  copy_f32<<<4, 256, 0, stream>>>(bk1, BQKV1, 1024);
  copy_f32<<<4, 256, 0, stream>>>(bq1, BQKV1 + 1024, 1024);
  copy_f32<<<4, 256, 0, stream>>>(bv1, BQKV1 + 2048, 1024);
  copy_f32<<<4, 256, 0, stream>>>(bk2, BKV2, 1024);
  copy_f32<<<4, 256, 0, stream>>>(bv2, BKV2 + 1024, 1024);

  // ---- self-attention block ----
  gemm8p<256, 0, 0><<<dim3(12, 32), 512, 0, stream>>>(XBF, WQKV1T, BQKV1, nullptr,
                                                      nullptr, QKV, NR, 3072, NE);
  transpose_v<<<dim3(64, 8, 16), tb, 0, stream>>>(QKV + 2048, 3072, VT);
  attn4w<1><<<512, 256, 0, stream>>>(QKV + 1024, 3072, QKV, 3072, VT, Obuf);
  gemm8p<128, 1, 0><<<dim3(8, 32), 512, 0, stream>>>(Obuf, WO1T, bo1, inp,
                                                     T0, nullptr, NR, NE, NE);
  ln_kernel<0, 1><<<NR, 256, 0, stream>>>(T0, lng, lnb, Af, ABF);

  // ---- cross-attention block ----
  cast_f32_bf16<<<8192, 256, 0, stream>>>(ctx, XBF, NR * NE / 4);
  gemm8p<256, 0, 0><<<dim3(8, 32), 512, 0, stream>>>(XBF, WKV2T, BKV2, nullptr,
                                                     nullptr, QKV, NR, 2048, NE);
  gemm8p<128, 0, 0><<<dim3(8, 32), 512, 0, stream>>>(ABF, WQ2T, bq2, nullptr,
                                                     nullptr, Q2, NR, NE, NE);
  transpose_v<<<dim3(64, 8, 16), tb, 0, stream>>>(QKV + 1024, 2048, VT);
  attn4w<0><<<512, 256, 0, stream>>>(Q2, 1024, QKV, 2048, VT, Obuf);
  gemm8p<128, 1, 0><<<dim3(8, 32), 512, 0, stream>>>(Obuf, WO2T, bo2, Af,
                                                     T0, nullptr, NR, NE, NE);
  ln_kernel<0, 1><<<NR, 256, 0, stream>>>(T0, lng, lnb, Af, ABF);

  // ---- FFN ----
  gemm8p<256, 0, 1><<<dim3(16, 32), 512, 0, stream>>>(ABF, W1T, b1, nullptr,
                                                      nullptr, MID, NR, NF, NE);
  gemm8p<128, 1, 0><<<dim3(8, 32), 512, 0, stream>>>(MID, W2T, b2, Af,
                                                     T0, nullptr, NR, NE, NF);
  ln_kernel<1, 0><<<NR, 256, 0, stream>>>(T0, lng, lnb, out, nullptr);
}

// Round 11
// 726.980 us; speedup vs baseline: 1.8223x; 1.0486x over previous
//
#include <hip/hip_runtime.h>

#define DEV __device__ __forceinline__

typedef unsigned short u16;
typedef __bf16 bf16x8 __attribute__((ext_vector_type(8)));
typedef bf16x8 __attribute__((may_alias)) bf16x8a;
typedef float f32x4 __attribute__((ext_vector_type(4)));
typedef float f32x16 __attribute__((ext_vector_type(16)));

constexpr int NB = 4, NS = 2048, NE = 1024, NH = 4, NDH = 256, NF = 4096;
constexpr int NR = NB * NS;  // 8192 rows

DEV u16 f2bf(float f) {
  unsigned u = __float_as_uint(f);
  u += 0x7fff + ((u >> 16) & 1);
  return (u16)(u >> 16);
}

DEV f32x4 mfma16(bf16x8 a, bf16x8 b, f32x4 c) {
  return __builtin_amdgcn_mfma_f32_16x16x32_bf16(a, b, c, 0, 0, 0);
}
DEV f32x16 mfma32(bf16x8 a, bf16x8 b, f32x16 c) {
  return __builtin_amdgcn_mfma_f32_32x32x16_bf16(a, b, c, 0, 0, 0);
}

DEV bf16x8 ldfrag(const u16* p) { return *(const bf16x8a*)p; }

DEV void gload_lds16(const void* g, void* l) {
  __builtin_amdgcn_global_load_lds(
      (const __attribute__((address_space(1))) void*)g,
      (__attribute__((address_space(3))) void*)l, 16, 0, 0);
}

DEV void blockbar() {
  asm volatile("" ::: "memory");
  __builtin_amdgcn_s_barrier();
  asm volatile("" ::: "memory");
}

DEV unsigned packbf(float a, float b) {
  union { __bf16 h[2]; unsigned u; } x;
  x.h[0] = (__bf16)a; x.h[1] = (__bf16)b;
  return x.u;
}

// ---------------- elementwise cast f32 -> bf16 ----------------
__global__ void cast_f32_bf16(const float* __restrict__ in, u16* __restrict__ out, int n4) {
  int i = blockIdx.x * 256 + threadIdx.x;
  if (i >= n4) return;
  float4 v = ((const float4*)in)[i];
  ushort4 o;
  o.x = f2bf(v.x); o.y = f2bf(v.y); o.z = f2bf(v.z); o.w = f2bf(v.w);
  ((ushort4*)out)[i] = o;
}

// ---------------- batched transpose + cast: in[z][R][C] f32 -> out[z][C][R] bf16 ----------------
__global__ void transpose_cast(const float* __restrict__ in, u16* __restrict__ out, int R, int C) {
  __shared__ float t[32][33];
  size_t base = (size_t)blockIdx.z * R * C;
  int c0 = blockIdx.x * 32, r0 = blockIdx.y * 32;
  int x = threadIdx.x;
  for (int yy = threadIdx.y; yy < 32; yy += 8)
    t[yy][x] = in[base + (size_t)(r0 + yy) * C + c0 + x];
  __syncthreads();
  for (int yy = threadIdx.y; yy < 32; yy += 8)
    out[base + (size_t)(c0 + yy) * R + r0 + x] = f2bf(t[x][yy]);
}

// ---------------- V transpose: V[(b*S+s)*vstride + h*DH + d] -> Vt[(bh*DH+d)*S + s] ----------------
__global__ void transpose_v(const u16* __restrict__ V, int vstride, u16* __restrict__ Vt) {
  __shared__ u16 t[32][34];
  int bh = blockIdx.z, b = bh >> 2, h = bh & (NH - 1);
  int s0 = blockIdx.x * 32, d0 = blockIdx.y * 32;
  int x = threadIdx.x;
  for (int yy = threadIdx.y; yy < 32; yy += 8)
    t[yy][x] = V[(size_t)(b * NS + s0 + yy) * vstride + h * NDH + d0 + x];
  __syncthreads();
  for (int yy = threadIdx.y; yy < 32; yy += 8)
    Vt[((size_t)bh * NDH + d0 + yy) * NS + s0 + x] = t[x][yy];
}

// ---------------- small f32 copy (bias packing) ----------------
__global__ void copy_f32(const float* __restrict__ s, float* __restrict__ d, int n) {
  int i = blockIdx.x * 256 + threadIdx.x;
  if (i < n) d[i] = s[i];
}

// ---------------- 8-phase GEMM: C[M,N] = A[M,K] * Bt[N,K]^T (+bias,+res,relu) ----------------
// (R6 version - best measured GEMM total)
template<int BN, int OUTF32, int RELU>
__global__ __launch_bounds__(512, 1)
void gemm8p(const u16* __restrict__ A, const u16* __restrict__ Bt,
            const float* __restrict__ bias, const float* __restrict__ res,
            float* __restrict__ outF, u16* __restrict__ outB,
            int M, int N, int K)
{
  constexpr int NFRAG = BN / 64;          // n-frags per wave (4 or 2)
  __shared__ __align__(16) u16 smem[32768 + 2 * BN * 64];   // A: [2][256][64]; B: [2][BN][64]

  int tid = threadIdx.x, w = tid >> 6, lane = tid & 63;
  int lr = lane & 15, lk = lane >> 4;
  int wm = w >> 2, wn = w & 3;

  int flat = blockIdx.y * gridDim.x + blockIdx.x;
  int cpx = (gridDim.x * gridDim.y) >> 3;
  int swz = (flat & 7) * cpx + (flat >> 3);
  int bx = swz % gridDim.x, by = swz / gridDim.x;
  int rowBlk = by * 256, colBlk = bx * BN;

  f32x4 acc[8][NFRAG];
#pragma unroll
  for (int f = 0; f < 8; f++)
#pragma unroll
    for (int n = 0; n < NFRAG; n++) acc[f][n] = (f32x4){0.f, 0.f, 0.f, 0.f};

  int srow = lane >> 3;                    // 0..7 within 8-row group
  int scol = ((lane & 7) ^ (srow & 7)) * 8;  // pre-swizzled source granule

  const u16* gA = A + (size_t)rowBlk * K;
  const u16* gB = Bt + (size_t)colBlk * K;

  auto stageA = [&](int t, int p, int h) {
#pragma unroll
    for (int j = 0; j < 2; j++) {
      int rbase = h * 128 + (w * 2 + j) * 8;
      gload_lds16(gA + (size_t)(rbase + srow) * K + t * 64 + scol,
                  &smem[(p * 256 + rbase) * 64]);
    }
  };
  auto stageB = [&](int t, int p, int h) {
#pragma unroll
    for (int j = 0; j < 2; j++) {
      int rbase = h * 128 + (w * 2 + j) * 8;
      gload_lds16(gB + (size_t)(rbase + srow) * K + t * 64 + scol,
                  &smem[32768 + (p * BN + rbase) * 64]);
    }
  };

  // prologue: stage tile 0 into buf 0
  stageB(0, 0, 0);
  if (BN == 256) stageB(0, 0, 1);
  stageA(0, 0, 0);
  stageA(0, 0, 1);
  asm volatile("s_waitcnt vmcnt(0)" ::: "memory");
  blockbar();

  int NT = K >> 6;
  for (int t = 0; t < NT; t++) {
    int p = t & 1;
    bool pre = (t + 1 < NT);
    bf16x8 bf[NFRAG][2];
#pragma unroll
    for (int q = 0; q < 4; q++) {
      if (q == 0) {
#pragma unroll
        for (int n = 0; n < NFRAG; n++)
#pragma unroll
          for (int s = 0; s < 2; s++) {
            int rowB = wn * (BN >> 2) + n * 16 + lr;
            bf[n][s] = ldfrag(&smem[32768 + (p * BN + rowB) * 64 +
                                    (((s * 4 + lk) ^ (lr & 7)) * 8)]);
          }
      }
      bf16x8 af[2][2];
#pragma unroll
      for (int i = 0; i < 2; i++)
#pragma unroll
        for (int s = 0; s < 2; s++) {
          int rowA = wm * 128 + (q * 2 + i) * 16 + lr;
          af[i][s] = ldfrag(&smem[(p * 256 + rowA) * 64 +
                                  (((s * 4 + lk) ^ (lr & 7)) * 8)]);
        }
      if (pre) {
        if (BN == 256) {
          if (q == 0) { stageB(t + 1, p ^ 1, 0); stageB(t + 1, p ^ 1, 1); }
          else if (q == 1) stageA(t + 1, p ^ 1, 0);
          else if (q == 2) stageA(t + 1, p ^ 1, 1);
        } else {
          if (q == 0) stageB(t + 1, p ^ 1, 0);
          else if (q == 1) stageA(t + 1, p ^ 1, 0);
          else if (q == 2) stageA(t + 1, p ^ 1, 1);
        }
      }
      blockbar();
      asm volatile("s_waitcnt lgkmcnt(0)" ::: "memory");
      __builtin_amdgcn_s_setprio(1);
#pragma unroll
      for (int i = 0; i < 2; i++)
#pragma unroll
        for (int n = 0; n < NFRAG; n++)
#pragma unroll
          for (int s = 0; s < 2; s++)
            acc[q * 2 + i][n] = mfma16(af[i][s], bf[n][s], acc[q * 2 + i][n]);
      __builtin_amdgcn_s_setprio(0);
      if (q == 3) asm volatile("s_waitcnt vmcnt(0)" ::: "memory");
      blockbar();
    }
  }

  int orow0 = rowBlk + wm * 128;
  int ocol0 = colBlk + wn * (BN >> 2);
#pragma unroll
  for (int n = 0; n < NFRAG; n++) {
    int c = ocol0 + n * 16 + lr;
    float bv = bias[c];
#pragma unroll
    for (int f = 0; f < 8; f++) {
      int r0 = orow0 + f * 16 + lk * 4;
#pragma unroll
      for (int j = 0; j < 4; j++) {
        float v = acc[f][n][j] + bv;
        if (OUTF32) v += res[(size_t)(r0 + j) * N + c];
        if (RELU) v = fmaxf(v, 0.f);
        if (OUTF32) outF[(size_t)(r0 + j) * N + c] = v;
        else        outB[(size_t)(r0 + j) * N + c] = f2bf(v);
      }
    }
  }
}

// ---------------- flash attention: 8 waves, QBLK=128, KBLK=64, split-K pairs ----
// SPLIT=0: grid 256 = 16 bh * 16 qtiles, full key range, writes normalized bf16 O.
// SPLIT=1 (causal only): grid 512 = 16 qt(desc) * 2 half * 16 bh; block does half
//   of qt's key range (qt+1 tiles); writes unnormalized f32 partial O + (m,l).
template<int CAUSAL, int SPLIT>
__global__ __launch_bounds__(512, 2)
void attn8w(const u16* __restrict__ Qp, int qstride,
            const u16* __restrict__ Kp, int kstride,
            const u16* __restrict__ Vt, u16* __restrict__ O,
            float* __restrict__ Op, float* __restrict__ ml)
{
  __shared__ __align__(16) u16 smem[65536];   // 128KB

  int bidx = blockIdx.x;
  int bh, qt, kt0, kt1;
  if (SPLIT) {
    int qtIdx = bidx >> 5;         // 0..15, longest-first
    qt = 15 - qtIdx;
    int sub = bidx & 31;
    int half = sub >> 4;
    bh = sub & 15;
    kt0 = half ? (qt + 1) : 0;
    kt1 = half ? (2 * qt + 2) : (qt + 1);
  } else {
    bh = bidx & 15;
    qt = CAUSAL ? (15 - (bidx >> 4)) : (bidx >> 4);
    kt0 = 0;
    kt1 = CAUSAL ? (2 * qt + 2) : (NS / 64);
  }
  int b = bh >> 2, h = bh & 3;
  int tid = threadIdx.x, w = tid >> 6, lane = tid & 63;
  int L = lane & 31, hi = lane >> 5;
  int g = w >> 1, ks = w & 1;

  int qbase = qt * 128 + g * 32;

  const u16* qrow = Qp + (size_t)(b * NS + qbase + L) * qstride + h * NDH;
  bf16x8 qf[16];
#pragma unroll
  for (int s = 0; s < 16; s++) qf[s] = ldfrag(qrow + s * 16 + hi * 8);

  f32x16 oacc[8];
#pragma unroll
  for (int db = 0; db < 8; db++) oacc[db] = (f32x16){};
  float m = -1e30f, l = 0.f;

  constexpr float SC = 1.0f / NDH;

  const u16* kbase = Kp + (size_t)(b * NS) * kstride + h * NDH;
  const u16* vbase = Vt + (size_t)bh * NDH * NS;

  auto stage = [&](int kt, int buf) {
#pragma unroll
    for (int ii = 0; ii < 4; ii++) {
      int gi = w * 4 + ii;                       // 0..31
      int krow = 2 * gi + hi;
      int kcol = L ^ (krow & 31);
      gload_lds16(kbase + (size_t)(kt * 64 + krow) * kstride + kcol * 8,
                  &smem[buf * 16384 + gi * 512]);
      int vd = gi * 8 + (lane >> 3);
      int vg = (lane & 7) ^ (vd & 7);
      gload_lds16(vbase + (size_t)vd * NS + kt * 64 + vg * 8,
                  &smem[32768 + buf * 16384 + gi * 512]);
    }
  };

  stage(kt0, 0);
  asm volatile("" ::: "memory");     // group-order fence (R9 lesson)

  for (int kt = kt0; kt < kt1; kt++) {
    int buf = (kt - kt0) & 1;
    const u16* bK = &smem[buf * 16384];
    const u16* bV = &smem[32768 + buf * 16384];
    if (kt + 1 < kt1) {
      stage(kt + 1, buf ^ 1);
      asm volatile("s_waitcnt vmcnt(8)" ::: "memory");
    } else {
      asm volatile("s_waitcnt vmcnt(0)" ::: "memory");
    }
    blockbar();

    int ksub0 = kt * 64 + ks * 32;
    bool skip = CAUSAL && (ksub0 > qbase + 31);
    if (!skip) {
      bool domask = CAUSAL && (ksub0 + 31 > qbase);
      __builtin_amdgcn_s_setprio(1);
      f32x16 sa = (f32x16){};
#pragma unroll
      for (int s = 0; s < 16; s++) {
        int row = ks * 32 + L;
        bf16x8 kf = ldfrag(&bK[row * 256 + (((2 * s + hi) ^ L) & 31) * 8]);
        sa = mfma32(kf, qf[s], sa);
      }
      __builtin_amdgcn_s_setprio(0);

      float p[16];
      float tmax = -1e30f;
#pragma unroll
      for (int r = 0; r < 16; r++) {
        float v = sa[r] * SC;
        if (domask) {
          int key = ksub0 + (r & 3) + 8 * (r >> 2) + 4 * hi;
          if (key > qbase + L) v = -1e30f;
        }
        p[r] = v;
        tmax = fmaxf(tmax, v);
      }
      tmax = fmaxf(tmax, __shfl_xor(tmax, 32));

      float mn = m;
      if (!__all(tmax - m <= 5.0f)) {
        mn = fmaxf(m, tmax);
        float rs = __expf(m - mn);
        m = mn;
        l *= rs;
#pragma unroll
        for (int db = 0; db < 8; db++)
#pragma unroll
          for (int r = 0; r < 16; r++) oacc[db][r] *= rs;
      }
      float psum = 0.f;
#pragma unroll
      for (int r = 0; r < 16; r++) {
        p[r] = __expf(p[r] - mn);
        psum += p[r];
      }
      psum += __shfl_xor(psum, 32);
      l += psum;

      unsigned pk01 = packbf(p[0], p[1]),  pk23 = packbf(p[2], p[3]);
      unsigned pk45 = packbf(p[4], p[5]),  pk67 = packbf(p[6], p[7]);
      unsigned pk89 = packbf(p[8], p[9]),  pkab = packbf(p[10], p[11]);
      unsigned pkcd = packbf(p[12], p[13]), pkef = packbf(p[14], p[15]);
      unsigned s45 = (unsigned)__shfl_xor((int)pk45, 32);
      unsigned s67 = (unsigned)__shfl_xor((int)pk67, 32);
      unsigned s01 = (unsigned)__shfl_xor((int)pk01, 32);
      unsigned s23 = (unsigned)__shfl_xor((int)pk23, 32);
      unsigned scd = (unsigned)__shfl_xor((int)pkcd, 32);
      unsigned sef = (unsigned)__shfl_xor((int)pkef, 32);
      unsigned s89 = (unsigned)__shfl_xor((int)pk89, 32);
      unsigned sab = (unsigned)__shfl_xor((int)pkab, 32);
      union { unsigned u[4]; bf16x8 v; } fb0, fb1;
      fb0.u[0] = hi ? s45 : pk01;
      fb0.u[1] = hi ? s67 : pk23;
      fb0.u[2] = hi ? pk45 : s01;
      fb0.u[3] = hi ? pk67 : s23;
      fb1.u[0] = hi ? scd : pk89;
      fb1.u[1] = hi ? sef : pkab;
      fb1.u[2] = hi ? pkcd : s89;
      fb1.u[3] = hi ? pkef : sab;
      bf16x8 pb0 = fb0.v, pb1 = fb1.v;

      __builtin_amdgcn_s_setprio(1);
#pragma unroll
      for (int db = 0; db < 8; db++) {
        int vd = db * 32 + L;
        bf16x8 vf0 = ldfrag(&bV[vd * 64 + (((ks * 4 + hi) ^ (vd & 7)) & 7) * 8]);
        bf16x8 vf1 = ldfrag(&bV[vd * 64 + (((ks * 4 + 2 + hi) ^ (vd & 7)) & 7) * 8]);
        oacc[db] = mfma32(vf0, pb0, oacc[db]);
        oacc[db] = mfma32(vf1, pb1, oacc[db]);
      }
      __builtin_amdgcn_s_setprio(0);
    }
    blockbar();
  }

  // ---- merge wave pairs (w, w^1): disjoint keys, same 32 q-rows ----
  float* fsm = (float*)smem;
  blockbar();
  if (hi == 0) { fsm[w * 64 + L * 2] = m; fsm[w * 64 + L * 2 + 1] = l; }
  asm volatile("s_waitcnt lgkmcnt(0)" ::: "memory");
  blockbar();
  float mb = fsm[(w ^ 1) * 64 + L * 2];
  float lb = fsm[(w ^ 1) * 64 + L * 2 + 1];
  float M = fmaxf(m, mb);
  float eo = __expf(m - M);
  float lt = l * eo + lb * __expf(mb - M);
  asm volatile("s_waitcnt lgkmcnt(0)" ::: "memory");
  blockbar();
  float* reg = fsm + g * 8192;   // 32KB region per pair: [256 d][32 q] f32
  if (w & 1) {
#pragma unroll
    for (int db = 0; db < 8; db++)
#pragma unroll
      for (int r = 0; r < 16; r++) {
        int d = db * 32 + (r & 3) + 8 * (r >> 2) + 4 * hi;
        reg[d * 32 + L] = oacc[db][r] * eo;
      }
  }
  asm volatile("s_waitcnt lgkmcnt(0)" ::: "memory");
  blockbar();
  if (!(w & 1)) {
    if (SPLIT) {
      // unnormalized partial: Op[bidx][row 0..127][256], ml[bidx*128+row] = {M, lt}
      float* OpB = Op + (size_t)bidx * 32768 + (size_t)(g * 32 + L) * 256;
      if (hi == 0) {
        ml[((size_t)bidx * 128 + g * 32 + L) * 2]     = M;
        ml[((size_t)bidx * 128 + g * 32 + L) * 2 + 1] = lt;
      }
#pragma unroll
      for (int db = 0; db < 8; db++) {
#pragma unroll
        for (int rq = 0; rq < 4; rq++) {
          int d0 = db * 32 + rq * 8 + hi * 4;
          float4 v;
          v.x = oacc[db][rq * 4 + 0] * eo + reg[(d0 + 0) * 32 + L];
          v.y = oacc[db][rq * 4 + 1] * eo + reg[(d0 + 1) * 32 + L];
          v.z = oacc[db][rq * 4 + 2] * eo + reg[(d0 + 2) * 32 + L];
          v.w = oacc[db][rq * 4 + 3] * eo + reg[(d0 + 3) * 32 + L];
          *(float4*)(OpB + d0) = v;
        }
      }
    } else {
      float inv = 1.f / lt;
      size_t orow = (size_t)(b * NS + qbase + L) * NE + h * NDH;
#pragma unroll
      for (int db = 0; db < 8; db++) {
#pragma unroll
        for (int rq = 0; rq < 4; rq++) {
          int d0 = db * 32 + rq * 8 + hi * 4;
          float a0 = (oacc[db][rq * 4 + 0] * eo + reg[(d0 + 0) * 32 + L]) * inv;
          float a1 = (oacc[db][rq * 4 + 1] * eo + reg[(d0 + 1) * 32 + L]) * inv;
          float a2 = (oacc[db][rq * 4 + 2] * eo + reg[(d0 + 2) * 32 + L]) * inv;
          float a3 = (oacc[db][rq * 4 + 3] * eo + reg[(d0 + 3) * 32 + L]) * inv;
          uint2 wv;
          wv.x = packbf(a0, a1);
          wv.y = packbf(a2, a3);
          *(uint2*)&O[orow + d0] = wv;
        }
      }
    }
  }
}

// ---------------- merge the 2 split-K partials -> normalized bf16 O ----------------
// grid 256 = 16 qt * 16 bh; 256 threads; 2 threads per row (128 d each).
__global__ __launch_bounds__(256)
void merge_attn(const float* __restrict__ Op, const float* __restrict__ ml,
                u16* __restrict__ O)
{
  int blk = blockIdx.x;
  int qt = blk >> 4, bh = blk & 15;
  int b = bh >> 2, h = bh & 3;
  int p0 = (15 - qt) * 32 + bh;
  int p1 = p0 + 16;
  int tid = threadIdx.x;
  int row = tid >> 1;
  int dbase = (tid & 1) * 128;

  float m0 = ml[((size_t)p0 * 128 + row) * 2];
  float l0 = ml[((size_t)p0 * 128 + row) * 2 + 1];
  float m1 = ml[((size_t)p1 * 128 + row) * 2];
  float l1 = ml[((size_t)p1 * 128 + row) * 2 + 1];
  float M = fmaxf(m0, m1);
  float e0 = __expf(m0 - M), e1 = __expf(m1 - M);
  float inv = 1.f / (l0 * e0 + l1 * e1);
  const float* O0 = Op + ((size_t)p0 * 128 + row) * 256 + dbase;
  const float* O1 = Op + ((size_t)p1 * 128 + row) * 256 + dbase;
  u16* dst = O + (size_t)(b * NS + qt * 128 + row) * NE + h * NDH + dbase;
#pragma unroll
  for (int d = 0; d < 128; d += 4) {
    float4 a = *(const float4*)(O0 + d);
    float4 c = *(const float4*)(O1 + d);
    uint2 wv;
    wv.x = packbf((a.x * e0 + c.x * e1) * inv, (a.y * e0 + c.y * e1) * inv);
    wv.y = packbf((a.z * e0 + c.z * e1) * inv, (a.w * e0 + c.w * e1) * inv);
    *(uint2*)(dst + d) = wv;
  }
}

// ---------------- LayerNorm (eps=1e-3), optional relu, optional bf16 copy ----------------
template<int RELU, int WBF>
__global__ __launch_bounds__(256)
void ln_kernel(const float* __restrict__ x, const float* __restrict__ g,
               const float* __restrict__ bb, float* __restrict__ outF,
               u16* __restrict__ outB)
{
  int row = blockIdx.x, tid = threadIdx.x;
  float4 v = ((const float4*)(x + (size_t)row * NE))[tid];
  float s = v.x + v.y + v.z + v.w;
  float s2 = v.x * v.x + v.y * v.y + v.z * v.z + v.w * v.w;
#pragma unroll
  for (int off = 32; off; off >>= 1) {
    s += __shfl_xor(s, off);
    s2 += __shfl_xor(s2, off);
  }
  __shared__ float red[8];
  int wid = tid >> 6, lane = tid & 63;
  if (lane == 0) { red[wid] = s; red[4 + wid] = s2; }
  __syncthreads();
  s = red[0] + red[1] + red[2] + red[3];
  s2 = red[4] + red[5] + red[6] + red[7];
  float mean = s * (1.f / NE);
  float var = s2 * (1.f / NE) - mean * mean;
  float rstd = rsqrtf(var + 1e-3f);
  float4 gg = ((const float4*)g)[tid];
  float4 bv = ((const float4*)bb)[tid];
  float4 o;
  o.x = (v.x - mean) * rstd * gg.x + bv.x;
  o.y = (v.y - mean) * rstd * gg.y + bv.y;
  o.z = (v.z - mean) * rstd * gg.z + bv.z;
  o.w = (v.w - mean) * rstd * gg.w + bv.w;
  if (RELU) {
    o.x = fmaxf(o.x, 0.f); o.y = fmaxf(o.y, 0.f);
    o.z = fmaxf(o.z, 0.f); o.w = fmaxf(o.w, 0.f);
  }
  ((float4*)(outF + (size_t)row * NE))[tid] = o;
  if (WBF) {
    ushort4 ob;
    ob.x = f2bf(o.x); ob.y = f2bf(o.y); ob.z = f2bf(o.z); ob.w = f2bf(o.w);
    ((ushort4*)(outB + (size_t)row * NE))[tid] = ob;
  }
}

// ---------------- workspace layout (bytes) ----------------
constexpr size_t OFF_X    = 0;                       // 16 MB: Xbf -> O1 -> Ctxbf -> O2
constexpr size_t OFF_W    = OFF_X + 16777216;        // 32 MB packed weights
constexpr size_t OFF_BIAS = OFF_W + 33554432;        // packed biases
constexpr size_t OFF_QKV  = OFF_BIAS + 32768;        // 48 MB QKV1 / (KV2 + Q2) / MID
constexpr size_t OFF_VT   = OFF_QKV + 50331648;      // 16 MB Vt
constexpr size_t OFF_T0   = OFF_VT + 16777216;       // 32 MB f32 scratch; +Af = 64MB Op during attn1
constexpr size_t OFF_A    = OFF_T0 + 33554432;       // 32 MB f32 a / c
constexpr size_t OFF_ABF  = OFF_A + 33554432;        // 16 MB bf16 a / c; ml during attn1

extern "C" void kernel_launch(void* const* d_in, const int* in_sizes, int n_in,
                              void* d_out, int out_size, void* d_ws, size_t ws_size,
                              hipStream_t stream) {
  (void)in_sizes; (void)n_in; (void)out_size; (void)ws_size;
  const float* inp = (const float*)d_in[0];
  const float* ctx = (const float*)d_in[1];
  const float* Wk1 = (const float*)d_in[2];  const float* bk1 = (const float*)d_in[3];
  const float* Wq1 = (const float*)d_in[4];  const float* bq1 = (const float*)d_in[5];
  const float* Wv1 = (const float*)d_in[6];  const float* bv1 = (const float*)d_in[7];
  const float* Wo1 = (const float*)d_in[8];  const float* bo1 = (const float*)d_in[9];
  const float* Wk2 = (const float*)d_in[10]; const float* bk2 = (const float*)d_in[11];
  const float* Wq2 = (const float*)d_in[12]; const float* bq2 = (const float*)d_in[13];
  const float* Wv2 = (const float*)d_in[14]; const float* bv2 = (const float*)d_in[15];
  const float* Wo2 = (const float*)d_in[16]; const float* bo2 = (const float*)d_in[17];
  const float* lng = (const float*)d_in[18]; const float* lnb = (const float*)d_in[19];
  const float* W1  = (const float*)d_in[20]; const float* b1  = (const float*)d_in[21];
  const float* W2  = (const float*)d_in[22]; const float* b2  = (const float*)d_in[23];
  float* out = (float*)d_out;
  char* ws = (char*)d_ws;

  u16* XBF    = (u16*)(ws + OFF_X);        // also ctx-bf16 and attention-O buffer
  u16* WQKV1T = (u16*)(ws + OFF_W);        // rows [K|Q|V] x 1024
  u16* WKV2T  = WQKV1T + 3072 * 1024;      // rows [K|V] x 1024
  u16* WQ2T   = WKV2T + 2048 * 1024;
  u16* WO1T   = WQ2T + 1024 * 1024;
  u16* WO2T   = WO1T + 1024 * 1024;
  u16* W1T    = WO2T + 1024 * 1024;        // [4096][1024]
  u16* W2T    = W1T + 4096 * 1024;         // [1024][4096]
  float* BQKV1 = (float*)(ws + OFF_BIAS);  // 3072
  float* BKV2  = BQKV1 + 3072;             // 2048
  u16* QKV  = (u16*)(ws + OFF_QKV);        // [8192][3072] (self) / [8192][2048] KV2
  u16* Q2   = QKV + 8192 * 2048;           // [8192][1024]
  u16* VT   = (u16*)(ws + OFF_VT);         // [16][256][2048]
  u16* MID  = QKV;                         // [8192][4096] (aliases QKV+VT, both dead)
  float* T0 = (float*)(ws + OFF_T0);
  float* OpBuf = T0;                       // 64MB partial O (T0+Af, both dead in attn1)
  float* Af = (float*)(ws + OFF_A);
  u16* ABF  = (u16*)(ws + OFF_ABF);
  float* MlBuf = (float*)(ws + OFF_ABF);   // 512KB (ABF dead in attn1)
  u16* Obuf = XBF;

  dim3 tb(32, 8);

  // input cast + weight/bias packing
  cast_f32_bf16<<<8192, 256, 0, stream>>>(inp, XBF, NR * NE / 4);
  transpose_cast<<<dim3(8, 32, 4), tb, 0, stream>>>(Wk1, WQKV1T,               NE, NDH);
  transpose_cast<<<dim3(8, 32, 4), tb, 0, stream>>>(Wq1, WQKV1T + 1024 * 1024, NE, NDH);
  transpose_cast<<<dim3(8, 32, 4), tb, 0, stream>>>(Wv1, WQKV1T + 2048 * 1024, NE, NDH);
  transpose_cast<<<dim3(32, 32, 1), tb, 0, stream>>>(Wo1, WO1T, NE, NE);
  transpose_cast<<<dim3(8, 32, 4), tb, 0, stream>>>(Wk2, WKV2T,               NE, NDH);
  transpose_cast<<<dim3(8, 32, 4), tb, 0, stream>>>(Wv2, WKV2T + 1024 * 1024, NE, NDH);
  transpose_cast<<<dim3(8, 32, 4), tb, 0, stream>>>(Wq2, WQ2T, NE, NDH);
  transpose_cast<<<dim3(32, 32, 1), tb, 0, stream>>>(Wo2, WO2T, NE, NE);
  transpose_cast<<<dim3(128, 32, 1), tb, 0, stream>>>(W1, W1T, NE, NF);
  transpose_cast<<<dim3(32, 128, 1), tb, 0, stream>>>(W2, W2T, NF, NE);
  copy_f32<<<4, 256, 0, stream>>>(bk1, BQKV1, 1024);
  copy_f32<<<4, 256, 0, stream>>>(bq1, BQKV1 + 1024, 1024);
  copy_f32<<<4, 256, 0, stream>>>(bv1, BQKV1 + 2048, 1024);
  copy_f32<<<4, 256, 0, stream>>>(bk2, BKV2, 1024);
  copy_f32<<<4, 256, 0, stream>>>(bv2, BKV2 + 1024, 1024);

  // ---- self-attention block (split-K balanced causal) ----
  gemm8p<256, 0, 0><<<dim3(12, 32), 512, 0, stream>>>(XBF, WQKV1T, BQKV1, nullptr,
                                                      nullptr, QKV, NR, 3072, NE);
  transpose_v<<<dim3(64, 8, 16), tb, 0, stream>>>(QKV + 2048, 3072, VT);
  attn8w<1, 1><<<512, 512, 0, stream>>>(QKV + 1024, 3072, QKV, 3072, VT,
                                        nullptr, OpBuf, MlBuf);
  merge_attn<<<256, 256, 0, stream>>>(OpBuf, MlBuf, Obuf);
  gemm8p<128, 1, 0><<<dim3(8, 32), 512, 0, stream>>>(Obuf, WO1T, bo1, inp,
                                                     T0, nullptr, NR, NE, NE);
  ln_kernel<0, 1><<<NR, 256, 0, stream>>>(T0, lng, lnb, Af, ABF);

  // ---- cross-attention block ----
  cast_f32_bf16<<<8192, 256, 0, stream>>>(ctx, XBF, NR * NE / 4);
  gemm8p<256, 0, 0><<<dim3(8, 32), 512, 0, stream>>>(XBF, WKV2T, BKV2, nullptr,
                                                     nullptr, QKV, NR, 2048, NE);
  gemm8p<128, 0, 0><<<dim3(8, 32), 512, 0, stream>>>(ABF, WQ2T, bq2, nullptr,
                                                     nullptr, Q2, NR, NE, NE);
  transpose_v<<<dim3(64, 8, 16), tb, 0, stream>>>(QKV + 1024, 2048, VT);
  attn8w<0, 0><<<256, 512, 0, stream>>>(Q2, 1024, QKV, 2048, VT, Obuf,
                                        nullptr, nullptr);
  gemm8p<128, 1, 0><<<dim3(8, 32), 512, 0, stream>>>(Obuf, WO2T, bo2, Af,
                                                     T0, nullptr, NR, NE, NE);
  ln_kernel<0, 1><<<NR, 256, 0, stream>>>(T0, lng, lnb, Af, ABF);

  // ---- FFN ----
  gemm8p<256, 0, 1><<<dim3(16, 32), 512, 0, stream>>>(ABF, W1T, b1, nullptr,
                                                      nullptr, MID, NR, NF, NE);
  gemm8p<128, 1, 0><<<dim3(8, 32), 512, 0, stream>>>(MID, W2T, b2, Af,
                                                     T0, nullptr, NR, NE, NF);
  ln_kernel<1, 0><<<NR, 256, 0, stream>>>(T0, lng, lnb, out, nullptr);
}

// Round 12
// 713.018 us; speedup vs baseline: 1.8580x; 1.0196x over previous
//
#include <hip/hip_runtime.h>

#define DEV __device__ __forceinline__

typedef unsigned short u16;
typedef __bf16 bf16x8 __attribute__((ext_vector_type(8)));
typedef bf16x8 __attribute__((may_alias)) bf16x8a;
typedef float f32x4 __attribute__((ext_vector_type(4)));
typedef float f32x16 __attribute__((ext_vector_type(16)));

constexpr int NB = 4, NS = 2048, NE = 1024, NH = 4, NDH = 256, NF = 4096;
constexpr int NR = NB * NS;  // 8192 rows

DEV u16 f2bf(float f) {
  unsigned u = __float_as_uint(f);
  u += 0x7fff + ((u >> 16) & 1);
  return (u16)(u >> 16);
}

DEV f32x4 mfma16(bf16x8 a, bf16x8 b, f32x4 c) {
  return __builtin_amdgcn_mfma_f32_16x16x32_bf16(a, b, c, 0, 0, 0);
}
DEV f32x16 mfma32(bf16x8 a, bf16x8 b, f32x16 c) {
  return __builtin_amdgcn_mfma_f32_32x32x16_bf16(a, b, c, 0, 0, 0);
}

DEV bf16x8 ldfrag(const u16* p) { return *(const bf16x8a*)p; }

DEV void gload_lds16(const void* g, void* l) {
  __builtin_amdgcn_global_load_lds(
      (const __attribute__((address_space(1))) void*)g,
      (__attribute__((address_space(3))) void*)l, 16, 0, 0);
}

DEV void blockbar() {
  asm volatile("" ::: "memory");
  __builtin_amdgcn_s_barrier();
  asm volatile("" ::: "memory");
}

DEV unsigned packbf(float a, float b) {
  union { __bf16 h[2]; unsigned u; } x;
  x.h[0] = (__bf16)a; x.h[1] = (__bf16)b;
  return x.u;
}

// ---------------- elementwise cast f32 -> bf16 ----------------
__global__ void cast_f32_bf16(const float* __restrict__ in, u16* __restrict__ out, int n4) {
  int i = blockIdx.x * 256 + threadIdx.x;
  if (i >= n4) return;
  float4 v = ((const float4*)in)[i];
  ushort4 o;
  o.x = f2bf(v.x); o.y = f2bf(v.y); o.z = f2bf(v.z); o.w = f2bf(v.w);
  ((ushort4*)out)[i] = o;
}

// ---------------- batched transpose + cast: in[z][R][C] f32 -> out[z][C][R] bf16 ----------------
__global__ void transpose_cast(const float* __restrict__ in, u16* __restrict__ out, int R, int C) {
  __shared__ float t[32][33];
  size_t base = (size_t)blockIdx.z * R * C;
  int c0 = blockIdx.x * 32, r0 = blockIdx.y * 32;
  int x = threadIdx.x;
  for (int yy = threadIdx.y; yy < 32; yy += 8)
    t[yy][x] = in[base + (size_t)(r0 + yy) * C + c0 + x];
  __syncthreads();
  for (int yy = threadIdx.y; yy < 32; yy += 8)
    out[base + (size_t)(c0 + yy) * R + r0 + x] = f2bf(t[x][yy]);
}

// ---------------- V transpose: V[(b*S+s)*vstride + h*DH + d] -> Vt[(bh*DH+d)*S + s] ----------------
__global__ void transpose_v(const u16* __restrict__ V, int vstride, u16* __restrict__ Vt) {
  __shared__ u16 t[32][34];
  int bh = blockIdx.z, b = bh >> 2, h = bh & (NH - 1);
  int s0 = blockIdx.x * 32, d0 = blockIdx.y * 32;
  int x = threadIdx.x;
  for (int yy = threadIdx.y; yy < 32; yy += 8)
    t[yy][x] = V[(size_t)(b * NS + s0 + yy) * vstride + h * NDH + d0 + x];
  __syncthreads();
  for (int yy = threadIdx.y; yy < 32; yy += 8)
    Vt[((size_t)bh * NDH + d0 + yy) * NS + s0 + x] = t[x][yy];
}

// ---------------- small f32 copy (bias packing) ----------------
__global__ void copy_f32(const float* __restrict__ s, float* __restrict__ d, int n) {
  int i = blockIdx.x * 256 + threadIdx.x;
  if (i < n) d[i] = s[i];
}

// ---------------- 2-block GEMM: C[M,N] = A[M,K] * Bt[N,K]^T (+bias,+res,relu) ----------------
// BM=128, BN=128, BK=64, 256 threads (4 waves, wm=0, wn=w), double-buffered
// 64KB LDS -> 2 independent blocks/CU (inter-block overlap covers drain+barrier).
// ONE barrier + ONE vmcnt(0) per K-tile: stage(t+1) issued FIRST (max slack),
// then 20 ds_read frags (swizzled slot = g ^ (row&7), pre-swizzled global src,
// linear LDS dest), 32 MFMA, drain, barrier.
template<int OUTF32, int RELU>
__global__ __launch_bounds__(256, 2)
void gemm2b(const u16* __restrict__ A, const u16* __restrict__ Bt,
            const float* __restrict__ bias, const float* __restrict__ res,
            float* __restrict__ outF, u16* __restrict__ outB,
            int M, int N, int K)
{
  __shared__ __align__(16) u16 smem[32768];   // A [2][128][64] | B [2][128][64]

  int tid = threadIdx.x, w = tid >> 6, lane = tid & 63;
  int lr = lane & 15, lk = lane >> 4;

  int flat = blockIdx.y * gridDim.x + blockIdx.x;
  int cpx = (gridDim.x * gridDim.y) >> 3;
  int swz = (flat & 7) * cpx + (flat >> 3);
  int bx = swz % gridDim.x, by = swz / gridDim.x;
  int rowBlk = by * 128, colBlk = bx * 128;

  f32x4 acc[8][2];
#pragma unroll
  for (int f = 0; f < 8; f++)
#pragma unroll
    for (int n = 0; n < 2; n++) acc[f][n] = (f32x4){0.f, 0.f, 0.f, 0.f};

  int srow = lane >> 3;                       // 0..7
  int scol = ((lane & 7) ^ srow) * 8;         // pre-swizzled source granule

  const u16* gA = A + (size_t)rowBlk * K;
  const u16* gB = Bt + (size_t)colBlk * K;

  auto stageA = [&](int t, int p) {
#pragma unroll
    for (int j = 0; j < 4; j++) {
      int rbase = (w * 4 + j) * 8;
      gload_lds16(gA + (size_t)(rbase + srow) * K + (size_t)t * 64 + scol,
                  &smem[(p * 128 + rbase) * 64]);
    }
  };
  auto stageB = [&](int t, int p) {
#pragma unroll
    for (int j = 0; j < 4; j++) {
      int rbase = (w * 4 + j) * 8;
      gload_lds16(gB + (size_t)(rbase + srow) * K + (size_t)t * 64 + scol,
                  &smem[16384 + (p * 128 + rbase) * 64]);
    }
  };

  stageB(0, 0);
  asm volatile("" ::: "memory");
  stageA(0, 0);
  asm volatile("s_waitcnt vmcnt(0)" ::: "memory");
  blockbar();

  int NT = K >> 6;
  for (int t = 0; t < NT; t++) {
    int p = t & 1;
    if (t + 1 < NT) {
      stageB(t + 1, p ^ 1);
      asm volatile("" ::: "memory");
      stageA(t + 1, p ^ 1);
      asm volatile("" ::: "memory");
    }
    const u16* Ar = &smem[p * 8192];
    const u16* Br = &smem[16384 + p * 8192];
    bf16x8 bf[2][2], af[8][2];
#pragma unroll
    for (int n = 0; n < 2; n++)
#pragma unroll
      for (int s = 0; s < 2; s++) {
        int rowB = w * 32 + n * 16 + lr;
        bf[n][s] = ldfrag(&Br[rowB * 64 + (((s * 4 + lk) ^ (lr & 7)) * 8)]);
      }
#pragma unroll
    for (int f = 0; f < 8; f++)
#pragma unroll
      for (int s = 0; s < 2; s++) {
        int rowA = f * 16 + lr;
        af[f][s] = ldfrag(&Ar[rowA * 64 + (((s * 4 + lk) ^ (lr & 7)) * 8)]);
      }
    __builtin_amdgcn_s_setprio(1);
#pragma unroll
    for (int f = 0; f < 8; f++)
#pragma unroll
      for (int n = 0; n < 2; n++)
#pragma unroll
        for (int s = 0; s < 2; s++)
          acc[f][n] = mfma16(af[f][s], bf[n][s], acc[f][n]);
    __builtin_amdgcn_s_setprio(0);
    asm volatile("s_waitcnt vmcnt(0)" ::: "memory");
    blockbar();
  }

  int ocol0 = colBlk + w * 32;
#pragma unroll
  for (int n = 0; n < 2; n++) {
    int c = ocol0 + n * 16 + lr;
    float bv = bias[c];
#pragma unroll
    for (int f = 0; f < 8; f++) {
      int r0 = rowBlk + f * 16 + lk * 4;
#pragma unroll
      for (int j = 0; j < 4; j++) {
        float v = acc[f][n][j] + bv;
        if (OUTF32) v += res[(size_t)(r0 + j) * N + c];
        if (RELU) v = fmaxf(v, 0.f);
        if (OUTF32) outF[(size_t)(r0 + j) * N + c] = v;
        else        outB[(size_t)(r0 + j) * N + c] = f2bf(v);
      }
    }
  }
}

// ---------------- flash attention: 8 waves, QBLK=128, KBLK=64, split-K pairs ----
// SPLIT=0: grid 256 = 16 bh * 16 qtiles, full key range, writes normalized bf16 O.
// SPLIT=1 (causal only): grid 512 = 16 qt(desc) * 2 half * 16 bh; block does half
//   of qt's key range (qt+1 tiles); writes unnormalized f32 partial O + (m,l).
template<int CAUSAL, int SPLIT>
__global__ __launch_bounds__(512, 2)
void attn8w(const u16* __restrict__ Qp, int qstride,
            const u16* __restrict__ Kp, int kstride,
            const u16* __restrict__ Vt, u16* __restrict__ O,
            float* __restrict__ Op, float* __restrict__ ml)
{
  __shared__ __align__(16) u16 smem[65536];   // 128KB

  int bidx = blockIdx.x;
  int bh, qt, kt0, kt1;
  if (SPLIT) {
    int qtIdx = bidx >> 5;         // 0..15, longest-first
    qt = 15 - qtIdx;
    int sub = bidx & 31;
    int half = sub >> 4;
    bh = sub & 15;
    kt0 = half ? (qt + 1) : 0;
    kt1 = half ? (2 * qt + 2) : (qt + 1);
  } else {
    bh = bidx & 15;
    qt = CAUSAL ? (15 - (bidx >> 4)) : (bidx >> 4);
    kt0 = 0;
    kt1 = CAUSAL ? (2 * qt + 2) : (NS / 64);
  }
  int b = bh >> 2, h = bh & 3;
  int tid = threadIdx.x, w = tid >> 6, lane = tid & 63;
  int L = lane & 31, hi = lane >> 5;
  int g = w >> 1, ks = w & 1;

  int qbase = qt * 128 + g * 32;

  const u16* qrow = Qp + (size_t)(b * NS + qbase + L) * qstride + h * NDH;
  bf16x8 qf[16];
#pragma unroll
  for (int s = 0; s < 16; s++) qf[s] = ldfrag(qrow + s * 16 + hi * 8);

  f32x16 oacc[8];
#pragma unroll
  for (int db = 0; db < 8; db++) oacc[db] = (f32x16){};
  float m = -1e30f, l = 0.f;

  constexpr float SC = 1.0f / NDH;

  const u16* kbase = Kp + (size_t)(b * NS) * kstride + h * NDH;
  const u16* vbase = Vt + (size_t)bh * NDH * NS;

  auto stage = [&](int kt, int buf) {
#pragma unroll
    for (int ii = 0; ii < 4; ii++) {
      int gi = w * 4 + ii;                       // 0..31
      int krow = 2 * gi + hi;
      int kcol = L ^ (krow & 31);
      gload_lds16(kbase + (size_t)(kt * 64 + krow) * kstride + kcol * 8,
                  &smem[buf * 16384 + gi * 512]);
      int vd = gi * 8 + (lane >> 3);
      int vg = (lane & 7) ^ (vd & 7);
      gload_lds16(vbase + (size_t)vd * NS + kt * 64 + vg * 8,
                  &smem[32768 + buf * 16384 + gi * 512]);
    }
  };

  stage(kt0, 0);
  asm volatile("" ::: "memory");     // group-order fence (R9 lesson)

  for (int kt = kt0; kt < kt1; kt++) {
    int buf = (kt - kt0) & 1;
    const u16* bK = &smem[buf * 16384];
    const u16* bV = &smem[32768 + buf * 16384];
    if (kt + 1 < kt1) {
      stage(kt + 1, buf ^ 1);
      asm volatile("s_waitcnt vmcnt(8)" ::: "memory");
    } else {
      asm volatile("s_waitcnt vmcnt(0)" ::: "memory");
    }
    blockbar();

    int ksub0 = kt * 64 + ks * 32;
    bool skip = CAUSAL && (ksub0 > qbase + 31);
    if (!skip) {
      bool domask = CAUSAL && (ksub0 + 31 > qbase);
      __builtin_amdgcn_s_setprio(1);
      f32x16 sa = (f32x16){};
#pragma unroll
      for (int s = 0; s < 16; s++) {
        int row = ks * 32 + L;
        bf16x8 kf = ldfrag(&bK[row * 256 + (((2 * s + hi) ^ L) & 31) * 8]);
        sa = mfma32(kf, qf[s], sa);
      }
      __builtin_amdgcn_s_setprio(0);

      float p[16];
      float tmax = -1e30f;
#pragma unroll
      for (int r = 0; r < 16; r++) {
        float v = sa[r] * SC;
        if (domask) {
          int key = ksub0 + (r & 3) + 8 * (r >> 2) + 4 * hi;
          if (key > qbase + L) v = -1e30f;
        }
        p[r] = v;
        tmax = fmaxf(tmax, v);
      }
      tmax = fmaxf(tmax, __shfl_xor(tmax, 32));

      float mn = m;
      if (!__all(tmax - m <= 5.0f)) {
        mn = fmaxf(m, tmax);
        float rs = __expf(m - mn);
        m = mn;
        l *= rs;
#pragma unroll
        for (int db = 0; db < 8; db++)
#pragma unroll
          for (int r = 0; r < 16; r++) oacc[db][r] *= rs;
      }
      float psum = 0.f;
#pragma unroll
      for (int r = 0; r < 16; r++) {
        p[r] = __expf(p[r] - mn);
        psum += p[r];
      }
      psum += __shfl_xor(psum, 32);
      l += psum;

      unsigned pk01 = packbf(p[0], p[1]),  pk23 = packbf(p[2], p[3]);
      unsigned pk45 = packbf(p[4], p[5]),  pk67 = packbf(p[6], p[7]);
      unsigned pk89 = packbf(p[8], p[9]),  pkab = packbf(p[10], p[11]);
      unsigned pkcd = packbf(p[12], p[13]), pkef = packbf(p[14], p[15]);
      unsigned s45 = (unsigned)__shfl_xor((int)pk45, 32);
      unsigned s67 = (unsigned)__shfl_xor((int)pk67, 32);
      unsigned s01 = (unsigned)__shfl_xor((int)pk01, 32);
      unsigned s23 = (unsigned)__shfl_xor((int)pk23, 32);
      unsigned scd = (unsigned)__shfl_xor((int)pkcd, 32);
      unsigned sef = (unsigned)__shfl_xor((int)pkef, 32);
      unsigned s89 = (unsigned)__shfl_xor((int)pk89, 32);
      unsigned sab = (unsigned)__shfl_xor((int)pkab, 32);
      union { unsigned u[4]; bf16x8 v; } fb0, fb1;
      fb0.u[0] = hi ? s45 : pk01;
      fb0.u[1] = hi ? s67 : pk23;
      fb0.u[2] = hi ? pk45 : s01;
      fb0.u[3] = hi ? pk67 : s23;
      fb1.u[0] = hi ? scd : pk89;
      fb1.u[1] = hi ? sef : pkab;
      fb1.u[2] = hi ? pkcd : s89;
      fb1.u[3] = hi ? pkef : sab;
      bf16x8 pb0 = fb0.v, pb1 = fb1.v;

      __builtin_amdgcn_s_setprio(1);
#pragma unroll
      for (int db = 0; db < 8; db++) {
        int vd = db * 32 + L;
        bf16x8 vf0 = ldfrag(&bV[vd * 64 + (((ks * 4 + hi) ^ (vd & 7)) & 7) * 8]);
        bf16x8 vf1 = ldfrag(&bV[vd * 64 + (((ks * 4 + 2 + hi) ^ (vd & 7)) & 7) * 8]);
        oacc[db] = mfma32(vf0, pb0, oacc[db]);
        oacc[db] = mfma32(vf1, pb1, oacc[db]);
      }
      __builtin_amdgcn_s_setprio(0);
    }
    blockbar();
  }

  // ---- merge wave pairs (w, w^1): disjoint keys, same 32 q-rows ----
  float* fsm = (float*)smem;
  blockbar();
  if (hi == 0) { fsm[w * 64 + L * 2] = m; fsm[w * 64 + L * 2 + 1] = l; }
  asm volatile("s_waitcnt lgkmcnt(0)" ::: "memory");
  blockbar();
  float mb = fsm[(w ^ 1) * 64 + L * 2];
  float lb = fsm[(w ^ 1) * 64 + L * 2 + 1];
  float M = fmaxf(m, mb);
  float eo = __expf(m - M);
  float lt = l * eo + lb * __expf(mb - M);
  asm volatile("s_waitcnt lgkmcnt(0)" ::: "memory");
  blockbar();
  float* reg = fsm + g * 8192;   // 32KB region per pair: [256 d][32 q] f32
  if (w & 1) {
#pragma unroll
    for (int db = 0; db < 8; db++)
#pragma unroll
      for (int r = 0; r < 16; r++) {
        int d = db * 32 + (r & 3) + 8 * (r >> 2) + 4 * hi;
        reg[d * 32 + L] = oacc[db][r] * eo;
      }
  }
  asm volatile("s_waitcnt lgkmcnt(0)" ::: "memory");
  blockbar();
  if (!(w & 1)) {
    if (SPLIT) {
      float* OpB = Op + (size_t)bidx * 32768 + (size_t)(g * 32 + L) * 256;
      if (hi == 0) {
        ml[((size_t)bidx * 128 + g * 32 + L) * 2]     = M;
        ml[((size_t)bidx * 128 + g * 32 + L) * 2 + 1] = lt;
      }
#pragma unroll
      for (int db = 0; db < 8; db++) {
#pragma unroll
        for (int rq = 0; rq < 4; rq++) {
          int d0 = db * 32 + rq * 8 + hi * 4;
          float4 v;
          v.x = oacc[db][rq * 4 + 0] * eo + reg[(d0 + 0) * 32 + L];
          v.y = oacc[db][rq * 4 + 1] * eo + reg[(d0 + 1) * 32 + L];
          v.z = oacc[db][rq * 4 + 2] * eo + reg[(d0 + 2) * 32 + L];
          v.w = oacc[db][rq * 4 + 3] * eo + reg[(d0 + 3) * 32 + L];
          *(float4*)(OpB + d0) = v;
        }
      }
    } else {
      float inv = 1.f / lt;
      size_t orow = (size_t)(b * NS + qbase + L) * NE + h * NDH;
#pragma unroll
      for (int db = 0; db < 8; db++) {
#pragma unroll
        for (int rq = 0; rq < 4; rq++) {
          int d0 = db * 32 + rq * 8 + hi * 4;
          float a0 = (oacc[db][rq * 4 + 0] * eo + reg[(d0 + 0) * 32 + L]) * inv;
          float a1 = (oacc[db][rq * 4 + 1] * eo + reg[(d0 + 1) * 32 + L]) * inv;
          float a2 = (oacc[db][rq * 4 + 2] * eo + reg[(d0 + 2) * 32 + L]) * inv;
          float a3 = (oacc[db][rq * 4 + 3] * eo + reg[(d0 + 3) * 32 + L]) * inv;
          uint2 wv;
          wv.x = packbf(a0, a1);
          wv.y = packbf(a2, a3);
          *(uint2*)&O[orow + d0] = wv;
        }
      }
    }
  }
}

// ---------------- merge the 2 split-K partials -> normalized bf16 O ----------------
__global__ __launch_bounds__(256)
void merge_attn(const float* __restrict__ Op, const float* __restrict__ ml,
                u16* __restrict__ O)
{
  int blk = blockIdx.x;
  int qt = blk >> 4, bh = blk & 15;
  int b = bh >> 2, h = bh & 3;
  int p0 = (15 - qt) * 32 + bh;
  int p1 = p0 + 16;
  int tid = threadIdx.x;
  int row = tid >> 1;
  int dbase = (tid & 1) * 128;

  float m0 = ml[((size_t)p0 * 128 + row) * 2];
  float l0 = ml[((size_t)p0 * 128 + row) * 2 + 1];
  float m1 = ml[((size_t)p1 * 128 + row) * 2];
  float l1 = ml[((size_t)p1 * 128 + row) * 2 + 1];
  float M = fmaxf(m0, m1);
  float e0 = __expf(m0 - M), e1 = __expf(m1 - M);
  float inv = 1.f / (l0 * e0 + l1 * e1);
  const float* O0 = Op + ((size_t)p0 * 128 + row) * 256 + dbase;
  const float* O1 = Op + ((size_t)p1 * 128 + row) * 256 + dbase;
  u16* dst = O + (size_t)(b * NS + qt * 128 + row) * NE + h * NDH + dbase;
#pragma unroll
  for (int d = 0; d < 128; d += 4) {
    float4 a = *(const float4*)(O0 + d);
    float4 c = *(const float4*)(O1 + d);
    uint2 wv;
    wv.x = packbf((a.x * e0 + c.x * e1) * inv, (a.y * e0 + c.y * e1) * inv);
    wv.y = packbf((a.z * e0 + c.z * e1) * inv, (a.w * e0 + c.w * e1) * inv);
    *(uint2*)(dst + d) = wv;
  }
}

// ---------------- LayerNorm (eps=1e-3), optional relu, optional bf16 copy ----------------
template<int RELU, int WBF>
__global__ __launch_bounds__(256)
void ln_kernel(const float* __restrict__ x, const float* __restrict__ g,
               const float* __restrict__ bb, float* __restrict__ outF,
               u16* __restrict__ outB)
{
  int row = blockIdx.x, tid = threadIdx.x;
  float4 v = ((const float4*)(x + (size_t)row * NE))[tid];
  float s = v.x + v.y + v.z + v.w;
  float s2 = v.x * v.x + v.y * v.y + v.z * v.z + v.w * v.w;
#pragma unroll
  for (int off = 32; off; off >>= 1) {
    s += __shfl_xor(s, off);
    s2 += __shfl_xor(s2, off);
  }
  __shared__ float red[8];
  int wid = tid >> 6, lane = tid & 63;
  if (lane == 0) { red[wid] = s; red[4 + wid] = s2; }
  __syncthreads();
  s = red[0] + red[1] + red[2] + red[3];
  s2 = red[4] + red[5] + red[6] + red[7];
  float mean = s * (1.f / NE);
  float var = s2 * (1.f / NE) - mean * mean;
  float rstd = rsqrtf(var + 1e-3f);
  float4 gg = ((const float4*)g)[tid];
  float4 bv = ((const float4*)bb)[tid];
  float4 o;
  o.x = (v.x - mean) * rstd * gg.x + bv.x;
  o.y = (v.y - mean) * rstd * gg.y + bv.y;
  o.z = (v.z - mean) * rstd * gg.z + bv.z;
  o.w = (v.w - mean) * rstd * gg.w + bv.w;
  if (RELU) {
    o.x = fmaxf(o.x, 0.f); o.y = fmaxf(o.y, 0.f);
    o.z = fmaxf(o.z, 0.f); o.w = fmaxf(o.w, 0.f);
  }
  ((float4*)(outF + (size_t)row * NE))[tid] = o;
  if (WBF) {
    ushort4 ob;
    ob.x = f2bf(o.x); ob.y = f2bf(o.y); ob.z = f2bf(o.z); ob.w = f2bf(o.w);
    ((ushort4*)(outB + (size_t)row * NE))[tid] = ob;
  }
}

// ---------------- workspace layout (bytes) ----------------
constexpr size_t OFF_X    = 0;                       // 16 MB: Xbf -> O1 -> Ctxbf -> O2
constexpr size_t OFF_W    = OFF_X + 16777216;        // 32 MB packed weights
constexpr size_t OFF_BIAS = OFF_W + 33554432;        // packed biases
constexpr size_t OFF_QKV  = OFF_BIAS + 32768;        // 48 MB QKV1 / (KV2 + Q2) / MID
constexpr size_t OFF_VT   = OFF_QKV + 50331648;      // 16 MB Vt
constexpr size_t OFF_T0   = OFF_VT + 16777216;       // 32 MB f32 scratch; +Af = 64MB Op during attn1
constexpr size_t OFF_A    = OFF_T0 + 33554432;       // 32 MB f32 a / c
constexpr size_t OFF_ABF  = OFF_A + 33554432;        // 16 MB bf16 a / c; ml during attn1

extern "C" void kernel_launch(void* const* d_in, const int* in_sizes, int n_in,
                              void* d_out, int out_size, void* d_ws, size_t ws_size,
                              hipStream_t stream) {
  (void)in_sizes; (void)n_in; (void)out_size; (void)ws_size;
  const float* inp = (const float*)d_in[0];
  const float* ctx = (const float*)d_in[1];
  const float* Wk1 = (const float*)d_in[2];  const float* bk1 = (const float*)d_in[3];
  const float* Wq1 = (const float*)d_in[4];  const float* bq1 = (const float*)d_in[5];
  const float* Wv1 = (const float*)d_in[6];  const float* bv1 = (const float*)d_in[7];
  const float* Wo1 = (const float*)d_in[8];  const float* bo1 = (const float*)d_in[9];
  const float* Wk2 = (const float*)d_in[10]; const float* bk2 = (const float*)d_in[11];
  const float* Wq2 = (const float*)d_in[12]; const float* bq2 = (const float*)d_in[13];
  const float* Wv2 = (const float*)d_in[14]; const float* bv2 = (const float*)d_in[15];
  const float* Wo2 = (const float*)d_in[16]; const float* bo2 = (const float*)d_in[17];
  const float* lng = (const float*)d_in[18]; const float* lnb = (const float*)d_in[19];
  const float* W1  = (const float*)d_in[20]; const float* b1  = (const float*)d_in[21];
  const float* W2  = (const float*)d_in[22]; const float* b2  = (const float*)d_in[23];
  float* out = (float*)d_out;
  char* ws = (char*)d_ws;

  u16* XBF    = (u16*)(ws + OFF_X);        // also ctx-bf16 and attention-O buffer
  u16* WQKV1T = (u16*)(ws + OFF_W);        // rows [K|Q|V] x 1024
  u16* WKV2T  = WQKV1T + 3072 * 1024;      // rows [K|V] x 1024
  u16* WQ2T   = WKV2T + 2048 * 1024;
  u16* WO1T   = WQ2T + 1024 * 1024;
  u16* WO2T   = WO1T + 1024 * 1024;
  u16* W1T    = WO2T + 1024 * 1024;        // [4096][1024]
  u16* W2T    = W1T + 4096 * 1024;         // [1024][4096]
  float* BQKV1 = (float*)(ws + OFF_BIAS);  // 3072
  float* BKV2  = BQKV1 + 3072;             // 2048
  u16* QKV  = (u16*)(ws + OFF_QKV);        // [8192][3072] (self) / [8192][2048] KV2
  u16* Q2   = QKV + 8192 * 2048;           // [8192][1024]
  u16* VT   = (u16*)(ws + OFF_VT);         // [16][256][2048]
  u16* MID  = QKV;                         // [8192][4096] (aliases QKV+VT, both dead)
  float* T0 = (float*)(ws + OFF_T0);
  float* OpBuf = T0;                       // 64MB partial O (T0+Af, both dead in attn1)
  float* Af = (float*)(ws + OFF_A);
  u16* ABF  = (u16*)(ws + OFF_ABF);
  float* MlBuf = (float*)(ws + OFF_ABF);   // 512KB (ABF dead in attn1)
  u16* Obuf = XBF;

  dim3 tb(32, 8);

  // input cast + weight/bias packing
  cast_f32_bf16<<<8192, 256, 0, stream>>>(inp, XBF, NR * NE / 4);
  transpose_cast<<<dim3(8, 32, 4), tb, 0, stream>>>(Wk1, WQKV1T,               NE, NDH);
  transpose_cast<<<dim3(8, 32, 4), tb, 0, stream>>>(Wq1, WQKV1T + 1024 * 1024, NE, NDH);
  transpose_cast<<<dim3(8, 32, 4), tb, 0, stream>>>(Wv1, WQKV1T + 2048 * 1024, NE, NDH);
  transpose_cast<<<dim3(32, 32, 1), tb, 0, stream>>>(Wo1, WO1T, NE, NE);
  transpose_cast<<<dim3(8, 32, 4), tb, 0, stream>>>(Wk2, WKV2T,               NE, NDH);
  transpose_cast<<<dim3(8, 32, 4), tb, 0, stream>>>(Wv2, WKV2T + 1024 * 1024, NE, NDH);
  transpose_cast<<<dim3(8, 32, 4), tb, 0, stream>>>(Wq2, WQ2T, NE, NDH);
  transpose_cast<<<dim3(32, 32, 1), tb, 0, stream>>>(Wo2, WO2T, NE, NE);
  transpose_cast<<<dim3(128, 32, 1), tb, 0, stream>>>(W1, W1T, NE, NF);
  transpose_cast<<<dim3(32, 128, 1), tb, 0, stream>>>(W2, W2T, NF, NE);
  copy_f32<<<4, 256, 0, stream>>>(bk1, BQKV1, 1024);
  copy_f32<<<4, 256, 0, stream>>>(bq1, BQKV1 + 1024, 1024);
  copy_f32<<<4, 256, 0, stream>>>(bv1, BQKV1 + 2048, 1024);
  copy_f32<<<4, 256, 0, stream>>>(bk2, BKV2, 1024);
  copy_f32<<<4, 256, 0, stream>>>(bv2, BKV2 + 1024, 1024);

  // ---- self-attention block (split-K balanced causal) ----
  gemm2b<0, 0><<<dim3(24, 64), 256, 0, stream>>>(XBF, WQKV1T, BQKV1, nullptr,
                                                 nullptr, QKV, NR, 3072, NE);
  transpose_v<<<dim3(64, 8, 16), tb, 0, stream>>>(QKV + 2048, 3072, VT);
  attn8w<1, 1><<<512, 512, 0, stream>>>(QKV + 1024, 3072, QKV, 3072, VT,
                                        nullptr, OpBuf, MlBuf);
  merge_attn<<<256, 256, 0, stream>>>(OpBuf, MlBuf, Obuf);
  gemm2b<1, 0><<<dim3(8, 64), 256, 0, stream>>>(Obuf, WO1T, bo1, inp,
                                                T0, nullptr, NR, NE, NE);
  ln_kernel<0, 1><<<NR, 256, 0, stream>>>(T0, lng, lnb, Af, ABF);

  // ---- cross-attention block ----
  cast_f32_bf16<<<8192, 256, 0, stream>>>(ctx, XBF, NR * NE / 4);
  gemm2b<0, 0><<<dim3(16, 64), 256, 0, stream>>>(XBF, WKV2T, BKV2, nullptr,
                                                 nullptr, QKV, NR, 2048, NE);
  gemm2b<0, 0><<<dim3(8, 64), 256, 0, stream>>>(ABF, WQ2T, bq2, nullptr,
                                                nullptr, Q2, NR, NE, NE);
  transpose_v<<<dim3(64, 8, 16), tb, 0, stream>>>(QKV + 1024, 2048, VT);
  attn8w<0, 0><<<256, 512, 0, stream>>>(Q2, 1024, QKV, 2048, VT, Obuf,
                                        nullptr, nullptr);
  gemm2b<1, 0><<<dim3(8, 64), 256, 0, stream>>>(Obuf, WO2T, bo2, Af,
                                                T0, nullptr, NR, NE, NE);
  ln_kernel<0, 1><<<NR, 256, 0, stream>>>(T0, lng, lnb, Af, ABF);

  // ---- FFN ----
  gemm2b<0, 1><<<dim3(32, 64), 256, 0, stream>>>(ABF, W1T, b1, nullptr,
                                                 nullptr, MID, NR, NF, NE);
  gemm2b<1, 0><<<dim3(8, 64), 256, 0, stream>>>(MID, W2T, b2, Af,
                                                T0, nullptr, NR, NE, NF);
  ln_kernel<1, 0><<<NR, 256, 0, stream>>>(T0, lng, lnb, out, nullptr);
}